// Round 1
// baseline (1121.951 us; speedup 1.0000x reference)
//
#include <hip/hip_runtime.h>
#include <hip/hip_bf16.h>

#define N_NODES 100000
#define N_EDGES 800000
#define EDGE_GRID 2500
#define EDGE_SLOTS 5

typedef __attribute__((ext_vector_type(8))) short short8v;   // 8 bf16 = 4 VGPRs
typedef __attribute__((ext_vector_type(4))) float f32x4;

__device__ __forceinline__ unsigned short f2bf(float f) {
    __hip_bfloat16 b = __float2bfloat16(f);
    return *(unsigned short*)&b;
}
__device__ __forceinline__ float bf2f(unsigned short u) {
    return __uint_as_float((unsigned)u << 16);
}
__device__ __forceinline__ unsigned pack2(float lo, float hi) {
    return (unsigned)f2bf(lo) | ((unsigned)f2bf(hi) << 16);
}

// ---------- CSR build ----------
__global__ __launch_bounds__(256) void hist_dst(
    const int* __restrict__ dst, int* __restrict__ counts)
{
    int e = blockIdx.x * 256 + threadIdx.x;
    if (e < N_EDGES) atomicAdd(&counts[dst[e]], 1);
}

__global__ __launch_bounds__(256) void scan_p1(
    const int* __restrict__ in, int* __restrict__ partials, int n)
{
    __shared__ int ws[4];
    int t = threadIdx.x, lane = t & 63, wv = t >> 6;
    int base = blockIdx.x * 1024;
    int s = 0;
#pragma unroll
    for (int i = 0; i < 4; ++i) {
        int idx = base + i * 256 + t;
        s += (idx < n) ? in[idx] : 0;
    }
#pragma unroll
    for (int off = 1; off < 64; off <<= 1) s += __shfl_xor(s, off);
    if (lane == 0) ws[wv] = s;
    __syncthreads();
    if (t == 0) partials[blockIdx.x] = ws[0] + ws[1] + ws[2] + ws[3];
}

__global__ __launch_bounds__(64) void scan_p2(
    int* __restrict__ partials, int nb, int* __restrict__ total_out)
{
    int lane = threadIdx.x;
    int carry = 0;
    for (int base = 0; base < nb; base += 64) {
        int idx = base + lane;
        int v = (idx < nb) ? partials[idx] : 0;
        int s = v;
#pragma unroll
        for (int off = 1; off < 64; off <<= 1) {
            int w = __shfl_up(s, off);
            if (lane >= off) s += w;
        }
        if (idx < nb) partials[idx] = s - v + carry;
        carry += __shfl(s, 63);
    }
    if (lane == 0) *total_out = carry;
}

__global__ __launch_bounds__(256) void scan_p3(
    const int* __restrict__ in, int* __restrict__ out, int* __restrict__ cursor,
    const int* __restrict__ partials, int n)
{
    __shared__ int ws[4];
    __shared__ int wpre[4];
    __shared__ int s_tot;
    int t = threadIdx.x, lane = t & 63, wv = t >> 6;
    int base = blockIdx.x * 1024;
    int carry = partials[blockIdx.x];
    for (int sub = 0; sub < 4; ++sub) {
        int idx = base + sub * 256 + t;
        int v = (idx < n) ? in[idx] : 0;
        int s = v;
#pragma unroll
        for (int off = 1; off < 64; off <<= 1) {
            int w = __shfl_up(s, off);
            if (lane >= off) s += w;
        }
        if (lane == 63) ws[wv] = s;
        __syncthreads();
        if (t == 0) {
            int a = 0;
#pragma unroll
            for (int i = 0; i < 4; ++i) { wpre[i] = a; a += ws[i]; }
            s_tot = a;
        }
        __syncthreads();
        int excl = s - v + wpre[wv] + carry;
        if (idx < n) { out[idx] = excl; if (cursor) cursor[idx] = excl; }
        carry += s_tot;
        __syncthreads();
    }
}

__global__ __launch_bounds__(256) void scatter_edges(
    const int* __restrict__ dst, const int* __restrict__ src,
    int* __restrict__ cursor,
    int* __restrict__ edge_ord, int* __restrict__ src_ord,
    int* __restrict__ dst_ord)
{
    int e = blockIdx.x * 256 + threadIdx.x;
    if (e < N_EDGES) {
        int d = dst[e];
        int pos = atomicAdd(&cursor[d], 1);
        edge_ord[pos] = e;
        src_ord[pos] = src[e];
        dst_ord[pos] = d;
    }
}

// npieces[n] = number of 64-slot blocks node n's slot range touches
__global__ __launch_bounds__(256) void calc_npieces(
    const int* __restrict__ offsets, int* __restrict__ npieces)
{
    int n = blockIdx.x * 256 + threadIdx.x;
    if (n < N_NODES) {
        int b = offsets[n], e = offsets[n + 1];
        npieces[n] = (e > b) ? (((e - 1) >> 6) - (b >> 6) + 1) : 0;
    }
}

// ---------- fused weight prep: w3t,w5t | wcatt | mw1t,mw2t ----------
__global__ __launch_bounds__(256) void prep_weights(
    const float* __restrict__ W1, const float* __restrict__ W2,
    const float* __restrict__ W3, const float* __restrict__ W4,
    const float* __restrict__ W5, const float* __restrict__ W6,
    const float* __restrict__ mw1, const float* __restrict__ mw2,
    unsigned short* __restrict__ w3t, unsigned short* __restrict__ w5t,
    unsigned short* __restrict__ wcatt,
    unsigned short* __restrict__ mw1t, unsigned short* __restrict__ mw2t)
{
    int bid = blockIdx.x;
    if (bid < 64) {
        int t = bid * 256 + threadIdx.x;          // 0..16383
        int r = t >> 7, c = t & 127;
        w3t[c * 128 + r] = f2bf(W3[t]);
        w5t[c * 128 + r] = f2bf(W5[t]);
    } else if (bid < 320) {
        int t = (bid - 64) * 256 + threadIdx.x;   // 0..65535
        int n = t >> 7, k = t & 127;
        const float* Wm = (n < 128) ? W1 : (n < 256) ? W2 : (n < 384) ? W4 : W6;
        wcatt[t] = f2bf(Wm[k * 128 + (n & 127)]);
    } else {
        int t = (bid - 320) * 256 + threadIdx.x;  // 0..65535
        if (t < 32768) {
            int n = t >> 7, k = t & 127;
            mw1t[t] = f2bf(mw1[k * 256 + n]);
        } else {
            int s = t - 32768;
            int n = s >> 8, k = s & 255;
            mw2t[s] = f2bf(mw2[k * 128 + n]);
        }
    }
}

// ---------- node GEMM: [u|v|k] bf16 + hw6 f32 = h(f32) @ [W1|W2|W4|W6] ----------
__global__ __launch_bounds__(256) void gemm_node(
    const float* __restrict__ A, const unsigned short* __restrict__ Bt,
    unsigned short* __restrict__ uvkb, float* __restrict__ hw6f)
{
    const int t = threadIdx.x;
    const int lane = t & 63, wv = t >> 6;
    const int l15 = lane & 15, kg = lane >> 4;
    const int m0 = blockIdx.x * 64;
    const int n0 = blockIdx.y * 128;
    const int M = N_NODES, K = 128;

    int arow = m0 + wv * 16 + l15;
    int arow_c = arow < M ? arow : M - 1;
    const float* ap = A + (size_t)arow_c * K + kg * 8;

    f32x4 acc[8];
#pragma unroll
    for (int nt = 0; nt < 8; ++nt) acc[nt] = (f32x4){0.f, 0.f, 0.f, 0.f};

    for (int ko = 0; ko < K; ko += 32) {
        float4 f0 = *(const float4*)(ap + ko);
        float4 f1 = *(const float4*)(ap + ko + 4);
        short8v af;
        af[0] = (short)f2bf(f0.x); af[1] = (short)f2bf(f0.y);
        af[2] = (short)f2bf(f0.z); af[3] = (short)f2bf(f0.w);
        af[4] = (short)f2bf(f1.x); af[5] = (short)f2bf(f1.y);
        af[6] = (short)f2bf(f1.z); af[7] = (short)f2bf(f1.w);
#pragma unroll
        for (int nt = 0; nt < 8; ++nt) {
            short8v bf = *(const short8v*)(Bt + (size_t)(n0 + nt * 16 + l15) * K + ko + kg * 8);
            acc[nt] = __builtin_amdgcn_mfma_f32_16x16x32_bf16(af, bf, acc[nt], 0, 0, 0);
        }
    }
#pragma unroll
    for (int nt = 0; nt < 8; ++nt) {
#pragma unroll
        for (int r = 0; r < 4; ++r) {
            int row = m0 + wv * 16 + kg * 4 + r;
            if (row < M) {
                int col = n0 + nt * 16 + l15;
                float vfl = acc[nt][r];
                if (n0 < 384) uvkb[(size_t)row * 384 + col] = f2bf(vfl);
                else          hw6f[(size_t)row * 128 + col - 384] = vfl;
            }
        }
    }
}

// ---------- generic bf16 MFMA GEMM (MLP hidden) ----------
__global__ __launch_bounds__(256) void gemm_bf16(
    const unsigned short* __restrict__ A, const unsigned short* __restrict__ Bt,
    int M, int K, int Nc,
    const float* __restrict__ res, float* __restrict__ Cf,
    unsigned short* __restrict__ Cb, int do_relu)
{
    const int t = threadIdx.x;
    const int lane = t & 63, wv = t >> 6;
    const int l15 = lane & 15, kg = lane >> 4;
    const int m0 = blockIdx.x * 64;
    const int n0 = blockIdx.y * 128;

    int arow = m0 + wv * 16 + l15;
    int arow_c = arow < M ? arow : M - 1;
    const unsigned short* ap = A + (size_t)arow_c * K + kg * 8;

    f32x4 acc[8];
#pragma unroll
    for (int nt = 0; nt < 8; ++nt) acc[nt] = (f32x4){0.f, 0.f, 0.f, 0.f};

    for (int ko = 0; ko < K; ko += 32) {
        short8v af = *(const short8v*)(ap + ko);
#pragma unroll
        for (int nt = 0; nt < 8; ++nt) {
            short8v bf = *(const short8v*)(Bt + (size_t)(n0 + nt * 16 + l15) * K + ko + kg * 8);
            acc[nt] = __builtin_amdgcn_mfma_f32_16x16x32_bf16(af, bf, acc[nt], 0, 0, 0);
        }
    }
#pragma unroll
    for (int nt = 0; nt < 8; ++nt) {
#pragma unroll
        for (int r = 0; r < 4; ++r) {
            int row = m0 + wv * 16 + kg * 4 + r;
            if (row < M) {
                int col = n0 + nt * 16 + l15;
                float vfl = acc[nt][r];
                if (res) vfl += res[(size_t)row * Nc + col];
                if (do_relu) vfl = fmaxf(vfl, 0.f);
                if (Cf) Cf[(size_t)row * Nc + col] = vfl;
                else    Cb[(size_t)row * Nc + col] = f2bf(vfl);
            }
        }
    }
}

// ---------- mw2 GEMM + residual + LayerNorm fused (Nc = 128) ----------
__global__ __launch_bounds__(256) void gemm_bf16_ln(
    const unsigned short* __restrict__ A, const unsigned short* __restrict__ Bt,
    int M, int K, const float* __restrict__ res,
    const float* __restrict__ gamma, const float* __restrict__ beta,
    float* __restrict__ out)
{
    const int t = threadIdx.x;
    const int lane = t & 63, wv = t >> 6;
    const int l15 = lane & 15, kg = lane >> 4;
    const int m0 = blockIdx.x * 64;

    int arow = m0 + wv * 16 + l15;
    int arow_c = arow < M ? arow : M - 1;
    const unsigned short* ap = A + (size_t)arow_c * K + kg * 8;

    f32x4 acc[8];
#pragma unroll
    for (int nt = 0; nt < 8; ++nt) acc[nt] = (f32x4){0.f, 0.f, 0.f, 0.f};

    for (int ko = 0; ko < K; ko += 32) {
        short8v af = *(const short8v*)(ap + ko);
#pragma unroll
        for (int nt = 0; nt < 8; ++nt) {
            short8v bf = *(const short8v*)(Bt + (size_t)(nt * 16 + l15) * K + ko + kg * 8);
            acc[nt] = __builtin_amdgcn_mfma_f32_16x16x32_bf16(af, bf, acc[nt], 0, 0, 0);
        }
    }

    float gv[8], bv[8];
#pragma unroll
    for (int nt = 0; nt < 8; ++nt) {
        gv[nt] = gamma[nt * 16 + l15];
        bv[nt] = beta[nt * 16 + l15];
    }

#pragma unroll
    for (int r = 0; r < 4; ++r) {
        int row = m0 + wv * 16 + kg * 4 + r;
        int rc = row < M ? row : M - 1;
        float x[8];
        float s = 0.f;
#pragma unroll
        for (int nt = 0; nt < 8; ++nt) {
            x[nt] = acc[nt][r] + res[(size_t)rc * 128 + nt * 16 + l15];
            s += x[nt];
        }
#pragma unroll
        for (int off = 1; off < 16; off <<= 1) s += __shfl_xor(s, off);
        float mu = s * (1.f / 128.f);
        float ss = 0.f;
#pragma unroll
        for (int nt = 0; nt < 8; ++nt) {
            float d = x[nt] - mu;
            ss += d * d;
        }
#pragma unroll
        for (int off = 1; off < 16; off <<= 1) ss += __shfl_xor(ss, off);
        float rsv = rsqrtf(ss * (1.f / 128.f) + 1e-5f);
        if (row < M) {
#pragma unroll
            for (int nt = 0; nt < 8; ++nt)
                out[(size_t)row * 128 + nt * 16 + l15] =
                    (x[nt] - mu) * rsv * gv[nt] + bv[nt];
        }
    }
}

// ---------- fused edge pass + in-register segmented aggregation ----------
// v14: persistent blocks, EDGE_SLOTS slots each (slot = bid + j*EDGE_GRID).
// Software pipeline: e-row loads for slot i+1 issued at top of compute(i)
// (pre[] regs), written to the other e_s buffer mid-compute; segment metadata
// triple-buffered and produced two slots ahead by wave 0. ONE barrier/slot.
// u[src] is read scattered from uvkb (L2/L3-resident) -- u_s LDS dropped so
// the double e-buffer keeps LDS <= 40 KB (4 blocks/CU).
__global__ __launch_bounds__(256, 4) void edge_agg(
    const float* __restrict__ e_ij,
    const unsigned short* __restrict__ w3t, const unsigned short* __restrict__ w5t,
    const unsigned short* __restrict__ uvkb,
    const int* __restrict__ edge_ord, const int* __restrict__ src_ord,
    const int* __restrict__ dst_ord,
    const int* __restrict__ offsets, const int* __restrict__ ppos,
    float* __restrict__ dpart, float* __restrict__ apart)
{
    __shared__ unsigned short e_s[2][64 * 136];     // 2 x 17408 B, stride 136
    __shared__ int s_eid[3][64], s_src[3][64], s_dst[3][64];
    __shared__ int s_sb[3][64], s_se[3][64], s_pi[3][64];
    __shared__ int s_nseg[3];

    const int t  = threadIdx.x;
    const int lane = t & 63, wv = t >> 6;
    const int l15 = lane & 15, kg = lane >> 4;
    const int cb = wv * 32 + 2 * l15;              // this lane's col pair
    const float inv = 0.17677669529663687f;        // 1/sqrt(32)
    const int b0 = blockIdx.x;

    // ---- prologue: meta for slots 0,1 ----
    if (t < 64) {
        for (int j = 0; j < 2; ++j) {
            int slot = b0 + j * EDGE_GRID;
            int e0 = slot * 64;
            int eid = edge_ord[e0 + t];
            int sv  = src_ord[e0 + t];
            int d   = dst_ord[e0 + t];
            s_eid[j][t] = eid; s_src[j][t] = sv; s_dst[j][t] = d;
            int dprev = __shfl_up(d, 1);
            bool bnd = (t == 0) || (d != dprev);
            unsigned long long mask = __ballot(bnd);
            int sid = __popcll(mask & ((1ull << t) - 1ull));
            if (bnd) {
                s_sb[j][sid] = t;
                s_pi[j][sid] = ppos[d] + slot - (offsets[d] >> 6);
                if (t > 0) s_se[j][sid - 1] = t;
            }
            if (t == 63) {
                int ns = __popcll(mask);
                s_se[j][ns - 1] = 64;
                s_nseg[j] = ns;
            }
        }
    }
    __syncthreads();

    // ---- stage e(slot 0) directly ----
#pragma unroll
    for (int i = 0; i < 4; ++i) {
        int flat = t + i * 256;
        int row = flat >> 4, c8 = (flat & 15) * 8;
        const float* p = &e_ij[(size_t)s_eid[0][row] * 128 + c8];
        float4 f0 = *(const float4*)p;
        float4 f1 = *(const float4*)(p + 4);
        short8v pk;
        pk[0] = (short)f2bf(f0.x); pk[1] = (short)f2bf(f0.y);
        pk[2] = (short)f2bf(f0.z); pk[3] = (short)f2bf(f0.w);
        pk[4] = (short)f2bf(f1.x); pk[5] = (short)f2bf(f1.y);
        pk[6] = (short)f2bf(f1.z); pk[7] = (short)f2bf(f1.w);
        *(short8v*)(&e_s[0][row * 136 + c8]) = pk;
    }
    __syncthreads();

    for (int it = 0; it < EDGE_SLOTS; ++it) {
        const int cur = it & 1;
        const int mi  = it % 3;
        const int mi1 = (it + 1) % 3;
        const int mi2 = (it + 2) % 3;

        // ---- top: issue e-row prefetch for slot it+1 into regs ----
        float4 pre[8];
        if (it < EDGE_SLOTS - 1) {
#pragma unroll
            for (int i = 0; i < 4; ++i) {
                int flat = t + i * 256;
                int row = flat >> 4, c8 = (flat & 15) * 8;
                const float* p = &e_ij[(size_t)s_eid[mi1][row] * 128 + c8];
                pre[2 * i]     = *(const float4*)p;
                pre[2 * i + 1] = *(const float4*)(p + 4);
            }
        }
        // wave0: issue meta loads for slot it+2
        int m_eid = 0, m_src = 0, m_dst = 0;
        if (t < 64 && it < EDGE_SLOTS - 2) {
            int e0 = (b0 + (it + 2) * EDGE_GRID) * 64;
            m_eid = edge_ord[e0 + t];
            m_src = src_ord[e0 + t];
            m_dst = dst_ord[e0 + t];
        }

        const int nseg = __builtin_amdgcn_readfirstlane(s_nseg[mi]);
        float ex0[4][4], ex1[4][4];

        // ---- phase 1: W3 -> attn -> ex (f32, kept in regs) ----
        {
            const unsigned short* b3p0 = w3t + (size_t)(cb + 0) * 128 + kg * 8;
            const unsigned short* b3p1 = w3t + (size_t)(cb + 1) * 128 + kg * 8;
            f32x4 a3[4][2];
#pragma unroll
            for (int m = 0; m < 4; ++m) {
                a3[m][0] = (f32x4){0.f, 0.f, 0.f, 0.f};
                a3[m][1] = (f32x4){0.f, 0.f, 0.f, 0.f};
            }
#pragma unroll
            for (int kidx = 0; kidx < 4; ++kidx) {
                const int ko = kidx * 32;
                short8v b30 = *(const short8v*)(b3p0 + ko);
                short8v b31 = *(const short8v*)(b3p1 + ko);
#pragma unroll
                for (int m = 0; m < 4; ++m) {
                    short8v af = *(const short8v*)(&e_s[cur][(m * 16 + l15) * 136 + kg * 8 + ko]);
                    a3[m][0] = __builtin_amdgcn_mfma_f32_16x16x32_bf16(af, b30, a3[m][0], 0, 0, 0);
                    a3[m][1] = __builtin_amdgcn_mfma_f32_16x16x32_bf16(af, b31, a3[m][1], 0, 0, 0);
                }
            }
#pragma unroll
            for (int m = 0; m < 4; ++m) {
#pragma unroll
                for (int r = 0; r < 4; ++r) {
                    int le = m * 16 + kg * 4 + r;
                    int d  = s_dst[mi][le];
                    int sv = s_src[mi][le];
                    unsigned upk = *(const unsigned*)&uvkb[(size_t)sv * 384 + cb];
                    unsigned vpk = *(const unsigned*)&uvkb[(size_t)d * 384 + 128 + cb];
                    float u0 = bf2f((unsigned short)(upk & 0xffffu));
                    float u1 = bf2f((unsigned short)(upk >> 16));
                    float v0 = bf2f((unsigned short)(vpk & 0xffffu));
                    float v1 = bf2f((unsigned short)(vpk >> 16));
                    float at0 = u0 * (v0 + a3[m][0][r]) * inv;
                    float at1 = u1 * (v1 + a3[m][1][r]) * inv;
                    ex0[m][r] = __expf(fminf(at0, 80.f));
                    ex1[m][r] = __expf(fminf(at1, 80.f));
                }
            }
        }

        // ---- mid: retire prefetch regs -> e_s[nxt] (buffer free since
        //      barrier(it-1); gives loads ~phase-1 duration to land) ----
        if (it < EDGE_SLOTS - 1) {
#pragma unroll
            for (int i = 0; i < 4; ++i) {
                int flat = t + i * 256;
                int row = flat >> 4, c8 = (flat & 15) * 8;
                short8v pk;
                pk[0] = (short)f2bf(pre[2 * i].x);     pk[1] = (short)f2bf(pre[2 * i].y);
                pk[2] = (short)f2bf(pre[2 * i].z);     pk[3] = (short)f2bf(pre[2 * i].w);
                pk[4] = (short)f2bf(pre[2 * i + 1].x); pk[5] = (short)f2bf(pre[2 * i + 1].y);
                pk[6] = (short)f2bf(pre[2 * i + 1].z); pk[7] = (short)f2bf(pre[2 * i + 1].w);
                *(short8v*)(&e_s[cur ^ 1][row * 136 + c8]) = pk;
            }
        }

        // ---- phase 2: W5 -> ex*x5 (in a5, in place; k factored out) ----
        f32x4 a5[4][2];
        {
            const unsigned short* b5p0 = w5t + (size_t)(cb + 0) * 128 + kg * 8;
            const unsigned short* b5p1 = w5t + (size_t)(cb + 1) * 128 + kg * 8;
#pragma unroll
            for (int m = 0; m < 4; ++m) {
                a5[m][0] = (f32x4){0.f, 0.f, 0.f, 0.f};
                a5[m][1] = (f32x4){0.f, 0.f, 0.f, 0.f};
            }
#pragma unroll
            for (int kidx = 0; kidx < 4; ++kidx) {
                const int ko = kidx * 32;
                short8v b50 = *(const short8v*)(b5p0 + ko);
                short8v b51 = *(const short8v*)(b5p1 + ko);
#pragma unroll
                for (int m = 0; m < 4; ++m) {
                    short8v af = *(const short8v*)(&e_s[cur][(m * 16 + l15) * 136 + kg * 8 + ko]);
                    a5[m][0] = __builtin_amdgcn_mfma_f32_16x16x32_bf16(af, b50, a5[m][0], 0, 0, 0);
                    a5[m][1] = __builtin_amdgcn_mfma_f32_16x16x32_bf16(af, b51, a5[m][1], 0, 0, 0);
                }
            }
#pragma unroll
            for (int m = 0; m < 4; ++m) {
#pragma unroll
                for (int r = 0; r < 4; ++r) {
                    a5[m][0][r] = ex0[m][r] * a5[m][0][r];
                    a5[m][1][r] = ex1[m][r] * a5[m][1][r];
                }
            }
        }

        // ---- combined segmented reduce -> dpart, apart ----
        for (int sg = 0; sg < nseg; ++sg) {
            const int b  = __builtin_amdgcn_readfirstlane(s_sb[mi][sg]);
            const int e2 = __builtin_amdgcn_readfirstlane(s_se[mi][sg]);
            const int pi = __builtin_amdgcn_readfirstlane(s_pi[mi][sg]);
            float d0 = 0.f, d1 = 0.f, g0 = 0.f, g1 = 0.f;
#pragma unroll
            for (int m = 0; m < 4; ++m) {
                if (b < m * 16 + 16 && e2 > m * 16) {   // scalar branch: skip m-block
#pragma unroll
                    for (int r = 0; r < 4; ++r) {
                        int slot = m * 16 + kg * 4 + r;
                        bool in = (slot >= b) && (slot < e2);
                        d0 += in ? ex0[m][r] : 0.f;
                        d1 += in ? ex1[m][r] : 0.f;
                        g0 += in ? a5[m][0][r] : 0.f;
                        g1 += in ? a5[m][1][r] : 0.f;
                    }
                }
            }
            d0 += __shfl_xor(d0, 16); d0 += __shfl_xor(d0, 32);
            d1 += __shfl_xor(d1, 16); d1 += __shfl_xor(d1, 32);
            g0 += __shfl_xor(g0, 16); g0 += __shfl_xor(g0, 32);
            g1 += __shfl_xor(g1, 16); g1 += __shfl_xor(g1, 32);
            if (kg == 0) {
                *(float2*)&dpart[(size_t)pi * 128 + cb] = make_float2(d0, d1);
                *(float2*)&apart[(size_t)pi * 128 + cb] = make_float2(g0, g1);
            }
        }

        // ---- tail: wave0 ballots slot it+2 meta into meta[mi2] ----
        if (t < 64 && it < EDGE_SLOTS - 2) {
            int slot2 = b0 + (it + 2) * EDGE_GRID;
            s_eid[mi2][t] = m_eid; s_src[mi2][t] = m_src; s_dst[mi2][t] = m_dst;
            int dprev = __shfl_up(m_dst, 1);
            bool bnd = (t == 0) || (m_dst != dprev);
            unsigned long long mask = __ballot(bnd);
            int sid = __popcll(mask & ((1ull << t) - 1ull));
            if (bnd) {
                s_sb[mi2][sid] = t;
                s_pi[mi2][sid] = ppos[m_dst] + slot2 - (offsets[m_dst] >> 6);
                if (t > 0) s_se[mi2][sid - 1] = t;
            }
            if (t == 63) {
                int ns = __popcll(mask);
                s_se[mi2][ns - 1] = 64;
                s_nseg[mi2] = ns;
            }
        }
        __syncthreads();
    }
}

// ---------- node finalize: sum pieces, h1 = LN(hw6 + k + agg/denom) ----------
__global__ __launch_bounds__(256) void node_finalize(
    const float* __restrict__ hw6f, const unsigned short* __restrict__ uvkb,
    const float* __restrict__ dpart, const float* __restrict__ apart,
    const int* __restrict__ ppos,
    const float* __restrict__ gamma, const float* __restrict__ beta,
    float* __restrict__ h1, unsigned short* __restrict__ h1b)
{
    int n = blockIdx.x * 4 + (threadIdx.x >> 6);
    int lane = threadIdx.x & 63;
    int p0 = ppos[n], p1 = ppos[n + 1];
    float de0 = 0.f, de1 = 0.f, g0 = 0.f, g1 = 0.f;
    for (int j = p0; j < p1; ++j) {
        float2 dv = *(const float2*)&dpart[(size_t)j * 128 + lane * 2];
        float2 av = *(const float2*)&apart[(size_t)j * 128 + lane * 2];
        de0 += dv.x; de1 += dv.y;
        g0  += av.x; g1  += av.y;
    }
    unsigned kpk = *(const unsigned*)&uvkb[(size_t)n * 384 + 256 + lane * 2];
    float k0 = bf2f((unsigned short)(kpk & 0xffffu));
    float k1 = bf2f((unsigned short)(kpk >> 16));
    float2 hw = *(const float2*)&hw6f[(size_t)n * 128 + lane * 2];
    float x0 = hw.x + (de0 > 0.f ? k0 + g0 / de0 : 0.f);
    float x1 = hw.y + (de1 > 0.f ? k1 + g1 / de1 : 0.f);
    float s = x0 + x1;
#pragma unroll
    for (int off = 1; off < 64; off <<= 1) s += __shfl_xor(s, off);
    float mu = s * (1.f / 128.f);
    float d0 = x0 - mu, d1 = x1 - mu;
    float ss = d0 * d0 + d1 * d1;
#pragma unroll
    for (int off = 1; off < 64; off <<= 1) ss += __shfl_xor(ss, off);
    float rs = rsqrtf(ss * (1.f / 128.f) + 1e-5f);
    float2 g = *(const float2*)&gamma[lane * 2];
    float2 b = *(const float2*)&beta[lane * 2];
    float o0 = d0 * rs * g.x + b.x;
    float o1 = d1 * rs * g.y + b.y;
    size_t base = (size_t)n * 128 + lane * 2;
    *(float2*)&h1[base] = make_float2(o0, o1);
    *(unsigned*)&h1b[base] = pack2(o0, o1);
}

extern "C" void kernel_launch(void* const* d_in, const int* in_sizes, int n_in,
                              void* d_out, int out_size, void* d_ws, size_t ws_size,
                              hipStream_t stream)
{
    const float* h    = (const float*)d_in[0];
    const float* e_ij = (const float*)d_in[1];
    const float* W1   = (const float*)d_in[2];
    const float* W2   = (const float*)d_in[3];
    const float* W3   = (const float*)d_in[4];
    const float* W4   = (const float*)d_in[5];
    const float* W5   = (const float*)d_in[6];
    const float* W6   = (const float*)d_in[7];
    const float* ln_g = (const float*)d_in[8];
    const float* ln_b = (const float*)d_in[9];
    const float* mw1  = (const float*)d_in[10];
    const float* mw2  = (const float*)d_in[11];
    const int*   src  = (const int*)d_in[12];
    const int*   dst  = (const int*)d_in[13];
    float* out = (float*)d_out;

    float* ws = (float*)d_ws;
    // layout (float offsets); P_max = 112640 pieces (N + E/64 rounded up)
    float* hw6f  = ws;                                 // [100k][128]
    float* h1    = ws + 12800000;                      // [100k][128]
    float* dpart = ws + 25600000;                      // [112640][128] = 14,417,920
    float* apart = ws + 40100000;                      // [112640][128]
    unsigned short* uvkb    = (unsigned short*)(ws + 54600000);   // [100k][384]
    unsigned short* h1b     = (unsigned short*)(ws + 73800000);   // [100k][128]
    unsigned short* hiddenb = (unsigned short*)(ws + 80200000);   // [100k][256]
    unsigned short* w3t   = (unsigned short*)(ws + 93000000);     // [128][128]
    unsigned short* w5t   = w3t + 16384;
    unsigned short* wcatt = w5t + 16384;               // [512][128]
    unsigned short* mw1t  = wcatt + 65536;             // [256][128]
    unsigned short* mw2t  = mw1t + 32768;              // [128][256]
    int* ibase    = (int*)(ws + 93100000);
    int* counts   = ibase;                             // [N]
    int* offsets  = ibase + 100000;                    // [N+1]
    int* cursor   = ibase + 200001;                    // [N]
    int* npieces  = ibase + 300001;                    // [N]
    int* ppos     = ibase + 400001;                    // [N+1]
    int* partials = ibase + 500102;                    // [128]
    int* edge_ord = ibase + 500230;                    // [E]
    int* src_ord  = edge_ord + N_EDGES;                // [E]
    int* dst_ord  = src_ord + N_EDGES;                 // [E]

    dim3 blk(256);
    hipMemsetAsync(counts, 0, N_NODES * sizeof(int), stream);

    hist_dst<<<N_EDGES / 256, blk, 0, stream>>>(dst, counts);
    scan_p1<<<98, blk, 0, stream>>>(counts, partials, N_NODES);
    scan_p2<<<1, 64, 0, stream>>>(partials, 98, offsets + N_NODES);
    scan_p3<<<98, blk, 0, stream>>>(counts, offsets, cursor, partials, N_NODES);
    scatter_edges<<<N_EDGES / 256, blk, 0, stream>>>(dst, src, cursor,
                                                     edge_ord, src_ord, dst_ord);
    calc_npieces<<<391, blk, 0, stream>>>(offsets, npieces);
    scan_p1<<<98, blk, 0, stream>>>(npieces, partials, N_NODES);
    scan_p2<<<1, 64, 0, stream>>>(partials, 98, ppos + N_NODES);
    scan_p3<<<98, blk, 0, stream>>>(npieces, ppos, (int*)nullptr, partials, N_NODES);

    prep_weights<<<576, blk, 0, stream>>>(W1, W2, W3, W4, W5, W6, mw1, mw2,
                                          w3t, w5t, wcatt, mw1t, mw2t);

    // u|v|k (bf16) and hw6 (f32) = h @ [W1|W2|W4|W6]  (A read f32, cvt in-reg)
    gemm_node<<<dim3(1563, 4), blk, 0, stream>>>(h, wcatt, uvkb, hw6f);

    edge_agg<<<EDGE_GRID, blk, 0, stream>>>(e_ij, w3t, w5t, uvkb,
                                            edge_ord, src_ord, dst_ord,
                                            offsets, ppos, dpart, apart);

    node_finalize<<<N_NODES / 4, blk, 0, stream>>>(hw6f, uvkb, dpart, apart, ppos,
                                                   ln_g, ln_b, h1, h1b);

    // hidden = relu(h1 @ mw1)
    gemm_bf16<<<dim3(1563, 2), blk, 0, stream>>>(h1b, mw1t, N_NODES, 128, 256,
                                                 nullptr, nullptr, hiddenb, 1);
    // out = LN(hidden @ mw2 + h1)
    gemm_bf16_ln<<<1563, blk, 0, stream>>>(hiddenb, mw2t, N_NODES, 256,
                                           h1, ln_g, ln_b, out);
}

// Round 2
// 921.267 us; speedup vs baseline: 1.2178x; 1.2178x over previous
//
#include <hip/hip_runtime.h>
#include <hip/hip_bf16.h>

#define N_NODES 100000
#define N_EDGES 800000

typedef __attribute__((ext_vector_type(8))) short short8v;   // 8 bf16 = 4 VGPRs
typedef __attribute__((ext_vector_type(4))) float f32x4;

__device__ __forceinline__ unsigned short f2bf(float f) {
    __hip_bfloat16 b = __float2bfloat16(f);
    return *(unsigned short*)&b;
}
__device__ __forceinline__ float bf2f(unsigned short u) {
    return __uint_as_float((unsigned)u << 16);
}
__device__ __forceinline__ unsigned pack2(float lo, float hi) {
    return (unsigned)f2bf(lo) | ((unsigned)f2bf(hi) << 16);
}

// ---------- CSR build ----------
__global__ __launch_bounds__(256) void hist_dst(
    const int* __restrict__ dst, int* __restrict__ counts)
{
    int e = blockIdx.x * 256 + threadIdx.x;
    if (e < N_EDGES) atomicAdd(&counts[dst[e]], 1);
}

__global__ __launch_bounds__(256) void scan_p1(
    const int* __restrict__ in, int* __restrict__ partials, int n)
{
    __shared__ int ws[4];
    int t = threadIdx.x, lane = t & 63, wv = t >> 6;
    int base = blockIdx.x * 1024;
    int s = 0;
#pragma unroll
    for (int i = 0; i < 4; ++i) {
        int idx = base + i * 256 + t;
        s += (idx < n) ? in[idx] : 0;
    }
#pragma unroll
    for (int off = 1; off < 64; off <<= 1) s += __shfl_xor(s, off);
    if (lane == 0) ws[wv] = s;
    __syncthreads();
    if (t == 0) partials[blockIdx.x] = ws[0] + ws[1] + ws[2] + ws[3];
}

__global__ __launch_bounds__(64) void scan_p2(
    int* __restrict__ partials, int nb, int* __restrict__ total_out)
{
    int lane = threadIdx.x;
    int carry = 0;
    for (int base = 0; base < nb; base += 64) {
        int idx = base + lane;
        int v = (idx < nb) ? partials[idx] : 0;
        int s = v;
#pragma unroll
        for (int off = 1; off < 64; off <<= 1) {
            int w = __shfl_up(s, off);
            if (lane >= off) s += w;
        }
        if (idx < nb) partials[idx] = s - v + carry;
        carry += __shfl(s, 63);
    }
    if (lane == 0) *total_out = carry;
}

__global__ __launch_bounds__(256) void scan_p3(
    const int* __restrict__ in, int* __restrict__ out, int* __restrict__ cursor,
    const int* __restrict__ partials, int n)
{
    __shared__ int ws[4];
    __shared__ int wpre[4];
    __shared__ int s_tot;
    int t = threadIdx.x, lane = t & 63, wv = t >> 6;
    int base = blockIdx.x * 1024;
    int carry = partials[blockIdx.x];
    for (int sub = 0; sub < 4; ++sub) {
        int idx = base + sub * 256 + t;
        int v = (idx < n) ? in[idx] : 0;
        int s = v;
#pragma unroll
        for (int off = 1; off < 64; off <<= 1) {
            int w = __shfl_up(s, off);
            if (lane >= off) s += w;
        }
        if (lane == 63) ws[wv] = s;
        __syncthreads();
        if (t == 0) {
            int a = 0;
#pragma unroll
            for (int i = 0; i < 4; ++i) { wpre[i] = a; a += ws[i]; }
            s_tot = a;
        }
        __syncthreads();
        int excl = s - v + wpre[wv] + carry;
        if (idx < n) { out[idx] = excl; if (cursor) cursor[idx] = excl; }
        carry += s_tot;
        __syncthreads();
    }
}

__global__ __launch_bounds__(256) void scatter_edges(
    const int* __restrict__ dst, const int* __restrict__ src,
    int* __restrict__ cursor,
    int* __restrict__ edge_ord, int* __restrict__ src_ord,
    int* __restrict__ dst_ord)
{
    int e = blockIdx.x * 256 + threadIdx.x;
    if (e < N_EDGES) {
        int d = dst[e];
        int pos = atomicAdd(&cursor[d], 1);
        edge_ord[pos] = e;
        src_ord[pos] = src[e];
        dst_ord[pos] = d;
    }
}

// npieces[n] = number of 64-slot blocks node n's slot range touches
__global__ __launch_bounds__(256) void calc_npieces(
    const int* __restrict__ offsets, int* __restrict__ npieces)
{
    int n = blockIdx.x * 256 + threadIdx.x;
    if (n < N_NODES) {
        int b = offsets[n], e = offsets[n + 1];
        npieces[n] = (e > b) ? (((e - 1) >> 6) - (b >> 6) + 1) : 0;
    }
}

// ---------- fused weight prep: w3t,w5t | wcatt | mw1t,mw2t ----------
__global__ __launch_bounds__(256) void prep_weights(
    const float* __restrict__ W1, const float* __restrict__ W2,
    const float* __restrict__ W3, const float* __restrict__ W4,
    const float* __restrict__ W5, const float* __restrict__ W6,
    const float* __restrict__ mw1, const float* __restrict__ mw2,
    unsigned short* __restrict__ w3t, unsigned short* __restrict__ w5t,
    unsigned short* __restrict__ wcatt,
    unsigned short* __restrict__ mw1t, unsigned short* __restrict__ mw2t)
{
    int bid = blockIdx.x;
    if (bid < 64) {
        int t = bid * 256 + threadIdx.x;          // 0..16383
        int r = t >> 7, c = t & 127;
        w3t[c * 128 + r] = f2bf(W3[t]);
        w5t[c * 128 + r] = f2bf(W5[t]);
    } else if (bid < 320) {
        int t = (bid - 64) * 256 + threadIdx.x;   // 0..65535
        int n = t >> 7, k = t & 127;
        const float* Wm = (n < 128) ? W1 : (n < 256) ? W2 : (n < 384) ? W4 : W6;
        wcatt[t] = f2bf(Wm[k * 128 + (n & 127)]);
    } else {
        int t = (bid - 320) * 256 + threadIdx.x;  // 0..65535
        if (t < 32768) {
            int n = t >> 7, k = t & 127;
            mw1t[t] = f2bf(mw1[k * 256 + n]);
        } else {
            int s = t - 32768;
            int n = s >> 8, k = s & 255;
            mw2t[s] = f2bf(mw2[k * 128 + n]);
        }
    }
}

// ---------- node GEMM: [u|v|k] bf16 + hw6 f32 = h(f32) @ [W1|W2|W4|W6] ----------
__global__ __launch_bounds__(256) void gemm_node(
    const float* __restrict__ A, const unsigned short* __restrict__ Bt,
    unsigned short* __restrict__ uvkb, float* __restrict__ hw6f)
{
    const int t = threadIdx.x;
    const int lane = t & 63, wv = t >> 6;
    const int l15 = lane & 15, kg = lane >> 4;
    const int m0 = blockIdx.x * 64;
    const int n0 = blockIdx.y * 128;
    const int M = N_NODES, K = 128;

    int arow = m0 + wv * 16 + l15;
    int arow_c = arow < M ? arow : M - 1;
    const float* ap = A + (size_t)arow_c * K + kg * 8;

    f32x4 acc[8];
#pragma unroll
    for (int nt = 0; nt < 8; ++nt) acc[nt] = (f32x4){0.f, 0.f, 0.f, 0.f};

    for (int ko = 0; ko < K; ko += 32) {
        float4 f0 = *(const float4*)(ap + ko);
        float4 f1 = *(const float4*)(ap + ko + 4);
        short8v af;
        af[0] = (short)f2bf(f0.x); af[1] = (short)f2bf(f0.y);
        af[2] = (short)f2bf(f0.z); af[3] = (short)f2bf(f0.w);
        af[4] = (short)f2bf(f1.x); af[5] = (short)f2bf(f1.y);
        af[6] = (short)f2bf(f1.z); af[7] = (short)f2bf(f1.w);
#pragma unroll
        for (int nt = 0; nt < 8; ++nt) {
            short8v bf = *(const short8v*)(Bt + (size_t)(n0 + nt * 16 + l15) * K + ko + kg * 8);
            acc[nt] = __builtin_amdgcn_mfma_f32_16x16x32_bf16(af, bf, acc[nt], 0, 0, 0);
        }
    }
#pragma unroll
    for (int nt = 0; nt < 8; ++nt) {
#pragma unroll
        for (int r = 0; r < 4; ++r) {
            int row = m0 + wv * 16 + kg * 4 + r;
            if (row < M) {
                int col = n0 + nt * 16 + l15;
                float vfl = acc[nt][r];
                if (n0 < 384) uvkb[(size_t)row * 384 + col] = f2bf(vfl);
                else          hw6f[(size_t)row * 128 + col - 384] = vfl;
            }
        }
    }
}

// ---------- generic bf16 MFMA GEMM (MLP hidden) ----------
__global__ __launch_bounds__(256) void gemm_bf16(
    const unsigned short* __restrict__ A, const unsigned short* __restrict__ Bt,
    int M, int K, int Nc,
    const float* __restrict__ res, float* __restrict__ Cf,
    unsigned short* __restrict__ Cb, int do_relu)
{
    const int t = threadIdx.x;
    const int lane = t & 63, wv = t >> 6;
    const int l15 = lane & 15, kg = lane >> 4;
    const int m0 = blockIdx.x * 64;
    const int n0 = blockIdx.y * 128;

    int arow = m0 + wv * 16 + l15;
    int arow_c = arow < M ? arow : M - 1;
    const unsigned short* ap = A + (size_t)arow_c * K + kg * 8;

    f32x4 acc[8];
#pragma unroll
    for (int nt = 0; nt < 8; ++nt) acc[nt] = (f32x4){0.f, 0.f, 0.f, 0.f};

    for (int ko = 0; ko < K; ko += 32) {
        short8v af = *(const short8v*)(ap + ko);
#pragma unroll
        for (int nt = 0; nt < 8; ++nt) {
            short8v bf = *(const short8v*)(Bt + (size_t)(n0 + nt * 16 + l15) * K + ko + kg * 8);
            acc[nt] = __builtin_amdgcn_mfma_f32_16x16x32_bf16(af, bf, acc[nt], 0, 0, 0);
        }
    }
#pragma unroll
    for (int nt = 0; nt < 8; ++nt) {
#pragma unroll
        for (int r = 0; r < 4; ++r) {
            int row = m0 + wv * 16 + kg * 4 + r;
            if (row < M) {
                int col = n0 + nt * 16 + l15;
                float vfl = acc[nt][r];
                if (res) vfl += res[(size_t)row * Nc + col];
                if (do_relu) vfl = fmaxf(vfl, 0.f);
                if (Cf) Cf[(size_t)row * Nc + col] = vfl;
                else    Cb[(size_t)row * Nc + col] = f2bf(vfl);
            }
        }
    }
}

// ---------- mw2 GEMM + residual + LayerNorm fused (Nc = 128) ----------
__global__ __launch_bounds__(256) void gemm_bf16_ln(
    const unsigned short* __restrict__ A, const unsigned short* __restrict__ Bt,
    int M, int K, const float* __restrict__ res,
    const float* __restrict__ gamma, const float* __restrict__ beta,
    float* __restrict__ out)
{
    const int t = threadIdx.x;
    const int lane = t & 63, wv = t >> 6;
    const int l15 = lane & 15, kg = lane >> 4;
    const int m0 = blockIdx.x * 64;

    int arow = m0 + wv * 16 + l15;
    int arow_c = arow < M ? arow : M - 1;
    const unsigned short* ap = A + (size_t)arow_c * K + kg * 8;

    f32x4 acc[8];
#pragma unroll
    for (int nt = 0; nt < 8; ++nt) acc[nt] = (f32x4){0.f, 0.f, 0.f, 0.f};

    for (int ko = 0; ko < K; ko += 32) {
        short8v af = *(const short8v*)(ap + ko);
#pragma unroll
        for (int nt = 0; nt < 8; ++nt) {
            short8v bf = *(const short8v*)(Bt + (size_t)(nt * 16 + l15) * K + ko + kg * 8);
            acc[nt] = __builtin_amdgcn_mfma_f32_16x16x32_bf16(af, bf, acc[nt], 0, 0, 0);
        }
    }

    float gv[8], bv[8];
#pragma unroll
    for (int nt = 0; nt < 8; ++nt) {
        gv[nt] = gamma[nt * 16 + l15];
        bv[nt] = beta[nt * 16 + l15];
    }

#pragma unroll
    for (int r = 0; r < 4; ++r) {
        int row = m0 + wv * 16 + kg * 4 + r;
        int rc = row < M ? row : M - 1;
        float x[8];
        float s = 0.f;
#pragma unroll
        for (int nt = 0; nt < 8; ++nt) {
            x[nt] = acc[nt][r] + res[(size_t)rc * 128 + nt * 16 + l15];
            s += x[nt];
        }
#pragma unroll
        for (int off = 1; off < 16; off <<= 1) s += __shfl_xor(s, off);
        float mu = s * (1.f / 128.f);
        float ss = 0.f;
#pragma unroll
        for (int nt = 0; nt < 8; ++nt) {
            float d = x[nt] - mu;
            ss += d * d;
        }
#pragma unroll
        for (int off = 1; off < 16; off <<= 1) ss += __shfl_xor(ss, off);
        float rsv = rsqrtf(ss * (1.f / 128.f) + 1e-5f);
        if (row < M) {
#pragma unroll
            for (int nt = 0; nt < 8; ++nt)
                out[(size_t)row * 128 + nt * 16 + l15] =
                    (x[nt] - mu) * rsv * gv[nt] + bv[nt];
        }
    }
}

// ---------- fused edge pass + in-register segmented aggregation ----------
// v15: NO e-tile LDS staging. MFMA A-fragments (per-lane 32B slices of e_ij
// rows) are loaded directly from global, converted once, and fed to BOTH the
// W3 and W5 MFMAs in a single fused K-pass (same A for both weight matrices).
// 16 rows x 4 kg lanes cover each 128B-aligned span exactly once -> zero
// over-fetch, and the 16 independent 32B gathers per lane interleave with
// the MFMA stream (latency hidden by MLP instead of stage->barrier).
// ex is written in place over a3 (no extra register array -> no spills).
// LDS holds only the 1.6 KB segment metadata; one barrier per block.
__global__ __launch_bounds__(256) void edge_agg(
    const float* __restrict__ e_ij,
    const unsigned short* __restrict__ w3t, const unsigned short* __restrict__ w5t,
    const unsigned short* __restrict__ uvkb,
    const int* __restrict__ edge_ord, const int* __restrict__ src_ord,
    const int* __restrict__ dst_ord,
    const int* __restrict__ offsets, const int* __restrict__ ppos,
    float* __restrict__ dpart, float* __restrict__ apart)
{
    __shared__ int s_eid[64], s_src[64], s_dst[64];
    __shared__ int s_sb[64], s_se[64], s_pi[64];
    __shared__ int s_nseg;
    const int t  = threadIdx.x;
    const int e0 = blockIdx.x * 64;            // slot base

    if (t < 64) {   // wave 0 exactly
        s_eid[t] = edge_ord[e0 + t];
        s_src[t] = src_ord[e0 + t];
        int d = dst_ord[e0 + t];
        s_dst[t] = d;
        int dprev = __shfl_up(d, 1);
        bool bnd = (t == 0) || (d != dprev);
        unsigned long long mask = __ballot(bnd);
        int sid = __popcll(mask & ((1ull << t) - 1ull));
        if (bnd) {
            s_sb[sid] = t;
            s_pi[sid] = ppos[d] + (int)blockIdx.x - (offsets[d] >> 6);
            if (t > 0) s_se[sid - 1] = t;
        }
        if (t == 63) {
            int ns = __popcll(mask);
            s_se[ns - 1] = 64;
            s_nseg = ns;
        }
    }
    __syncthreads();

    const int lane = t & 63, wv = t >> 6;
    const int l15 = lane & 15, kg = lane >> 4;
    const int cb = wv * 32 + 2 * l15;          // this lane's col pair

    const float inv = 0.17677669529663687f;    // 1/sqrt(32)
    const int nseg = __builtin_amdgcn_readfirstlane(s_nseg);

    // each lane's 4 A-rows (edge ids for rows m*16 + l15)
    int eid[4];
#pragma unroll
    for (int m = 0; m < 4; ++m) eid[m] = s_eid[m * 16 + l15];

    // ---- fused K-pass: a3 = e@W3 cols, a5 = e@W5 cols (same A fragments) ----
    f32x4 a3[4][2], a5[4][2];
#pragma unroll
    for (int m = 0; m < 4; ++m) {
        a3[m][0] = (f32x4){0.f, 0.f, 0.f, 0.f};
        a3[m][1] = (f32x4){0.f, 0.f, 0.f, 0.f};
        a5[m][0] = (f32x4){0.f, 0.f, 0.f, 0.f};
        a5[m][1] = (f32x4){0.f, 0.f, 0.f, 0.f};
    }
    {
        const unsigned short* b3p0 = w3t + (size_t)(cb + 0) * 128 + kg * 8;
        const unsigned short* b3p1 = w3t + (size_t)(cb + 1) * 128 + kg * 8;
        const unsigned short* b5p0 = w5t + (size_t)(cb + 0) * 128 + kg * 8;
        const unsigned short* b5p1 = w5t + (size_t)(cb + 1) * 128 + kg * 8;
#pragma unroll
        for (int kidx = 0; kidx < 4; ++kidx) {
            const int ko = kidx * 32;
            short8v b30 = *(const short8v*)(b3p0 + ko);
            short8v b31 = *(const short8v*)(b3p1 + ko);
            short8v b50 = *(const short8v*)(b5p0 + ko);
            short8v b51 = *(const short8v*)(b5p1 + ko);
#pragma unroll
            for (int m = 0; m < 4; ++m) {
                const float* p = e_ij + (size_t)eid[m] * 128 + ko + kg * 8;
                float4 f0 = *(const float4*)p;
                float4 f1 = *(const float4*)(p + 4);
                short8v af;
                af[0] = (short)f2bf(f0.x); af[1] = (short)f2bf(f0.y);
                af[2] = (short)f2bf(f0.z); af[3] = (short)f2bf(f0.w);
                af[4] = (short)f2bf(f1.x); af[5] = (short)f2bf(f1.y);
                af[6] = (short)f2bf(f1.z); af[7] = (short)f2bf(f1.w);
                a3[m][0] = __builtin_amdgcn_mfma_f32_16x16x32_bf16(af, b30, a3[m][0], 0, 0, 0);
                a3[m][1] = __builtin_amdgcn_mfma_f32_16x16x32_bf16(af, b31, a3[m][1], 0, 0, 0);
                a5[m][0] = __builtin_amdgcn_mfma_f32_16x16x32_bf16(af, b50, a5[m][0], 0, 0, 0);
                a5[m][1] = __builtin_amdgcn_mfma_f32_16x16x32_bf16(af, b51, a5[m][1], 0, 0, 0);
            }
        }
    }

    // ---- epilogue: ex = exp(u*(v+x3)*inv) written IN PLACE over a3;
    //      then a5 *= ex ----
#pragma unroll
    for (int m = 0; m < 4; ++m) {
#pragma unroll
        for (int r = 0; r < 4; ++r) {
            int le = m * 16 + kg * 4 + r;
            int d  = s_dst[le];
            int sv = s_src[le];
            unsigned upk = *(const unsigned*)&uvkb[(size_t)sv * 384 + cb];
            unsigned vpk = *(const unsigned*)&uvkb[(size_t)d * 384 + 128 + cb];
            float u0 = bf2f((unsigned short)(upk & 0xffffu));
            float u1 = bf2f((unsigned short)(upk >> 16));
            float v0 = bf2f((unsigned short)(vpk & 0xffffu));
            float v1 = bf2f((unsigned short)(vpk >> 16));
            float at0 = u0 * (v0 + a3[m][0][r]) * inv;
            float at1 = u1 * (v1 + a3[m][1][r]) * inv;
            float ex0 = __expf(fminf(at0, 80.f));
            float ex1 = __expf(fminf(at1, 80.f));
            a3[m][0][r] = ex0;
            a3[m][1][r] = ex1;
            a5[m][0][r] = ex0 * a5[m][0][r];
            a5[m][1][r] = ex1 * a5[m][1][r];
        }
    }

    // ---- combined segmented reduce -> dpart, apart ----
    for (int sg = 0; sg < nseg; ++sg) {
        const int b  = __builtin_amdgcn_readfirstlane(s_sb[sg]);
        const int e2 = __builtin_amdgcn_readfirstlane(s_se[sg]);
        const int pi = __builtin_amdgcn_readfirstlane(s_pi[sg]);
        float d0 = 0.f, d1 = 0.f, g0 = 0.f, g1 = 0.f;
#pragma unroll
        for (int m = 0; m < 4; ++m) {
            if (b < m * 16 + 16 && e2 > m * 16) {   // scalar branch: skip m-block
#pragma unroll
                for (int r = 0; r < 4; ++r) {
                    int slot = m * 16 + kg * 4 + r;
                    bool in = (slot >= b) && (slot < e2);
                    d0 += in ? a3[m][0][r] : 0.f;
                    d1 += in ? a3[m][1][r] : 0.f;
                    g0 += in ? a5[m][0][r] : 0.f;
                    g1 += in ? a5[m][1][r] : 0.f;
                }
            }
        }
        d0 += __shfl_xor(d0, 16); d0 += __shfl_xor(d0, 32);
        d1 += __shfl_xor(d1, 16); d1 += __shfl_xor(d1, 32);
        g0 += __shfl_xor(g0, 16); g0 += __shfl_xor(g0, 32);
        g1 += __shfl_xor(g1, 16); g1 += __shfl_xor(g1, 32);
        if (kg == 0) {
            *(float2*)&dpart[(size_t)pi * 128 + cb] = make_float2(d0, d1);
            *(float2*)&apart[(size_t)pi * 128 + cb] = make_float2(g0, g1);
        }
    }
}

// ---------- node finalize: sum pieces, h1 = LN(hw6 + k + agg/denom) ----------
__global__ __launch_bounds__(256) void node_finalize(
    const float* __restrict__ hw6f, const unsigned short* __restrict__ uvkb,
    const float* __restrict__ dpart, const float* __restrict__ apart,
    const int* __restrict__ ppos,
    const float* __restrict__ gamma, const float* __restrict__ beta,
    float* __restrict__ h1, unsigned short* __restrict__ h1b)
{
    int n = blockIdx.x * 4 + (threadIdx.x >> 6);
    int lane = threadIdx.x & 63;
    int p0 = ppos[n], p1 = ppos[n + 1];
    float de0 = 0.f, de1 = 0.f, g0 = 0.f, g1 = 0.f;
    for (int j = p0; j < p1; ++j) {
        float2 dv = *(const float2*)&dpart[(size_t)j * 128 + lane * 2];
        float2 av = *(const float2*)&apart[(size_t)j * 128 + lane * 2];
        de0 += dv.x; de1 += dv.y;
        g0  += av.x; g1  += av.y;
    }
    unsigned kpk = *(const unsigned*)&uvkb[(size_t)n * 384 + 256 + lane * 2];
    float k0 = bf2f((unsigned short)(kpk & 0xffffu));
    float k1 = bf2f((unsigned short)(kpk >> 16));
    float2 hw = *(const float2*)&hw6f[(size_t)n * 128 + lane * 2];
    float x0 = hw.x + (de0 > 0.f ? k0 + g0 / de0 : 0.f);
    float x1 = hw.y + (de1 > 0.f ? k1 + g1 / de1 : 0.f);
    float s = x0 + x1;
#pragma unroll
    for (int off = 1; off < 64; off <<= 1) s += __shfl_xor(s, off);
    float mu = s * (1.f / 128.f);
    float d0 = x0 - mu, d1 = x1 - mu;
    float ss = d0 * d0 + d1 * d1;
#pragma unroll
    for (int off = 1; off < 64; off <<= 1) ss += __shfl_xor(ss, off);
    float rs = rsqrtf(ss * (1.f / 128.f) + 1e-5f);
    float2 g = *(const float2*)&gamma[lane * 2];
    float2 b = *(const float2*)&beta[lane * 2];
    float o0 = d0 * rs * g.x + b.x;
    float o1 = d1 * rs * g.y + b.y;
    size_t base = (size_t)n * 128 + lane * 2;
    *(float2*)&h1[base] = make_float2(o0, o1);
    *(unsigned*)&h1b[base] = pack2(o0, o1);
}

extern "C" void kernel_launch(void* const* d_in, const int* in_sizes, int n_in,
                              void* d_out, int out_size, void* d_ws, size_t ws_size,
                              hipStream_t stream)
{
    const float* h    = (const float*)d_in[0];
    const float* e_ij = (const float*)d_in[1];
    const float* W1   = (const float*)d_in[2];
    const float* W2   = (const float*)d_in[3];
    const float* W3   = (const float*)d_in[4];
    const float* W4   = (const float*)d_in[5];
    const float* W5   = (const float*)d_in[6];
    const float* W6   = (const float*)d_in[7];
    const float* ln_g = (const float*)d_in[8];
    const float* ln_b = (const float*)d_in[9];
    const float* mw1  = (const float*)d_in[10];
    const float* mw2  = (const float*)d_in[11];
    const int*   src  = (const int*)d_in[12];
    const int*   dst  = (const int*)d_in[13];
    float* out = (float*)d_out;

    float* ws = (float*)d_ws;
    // layout (float offsets); P_max = 112640 pieces (N + E/64 rounded up)
    float* hw6f  = ws;                                 // [100k][128]
    float* h1    = ws + 12800000;                      // [100k][128]
    float* dpart = ws + 25600000;                      // [112640][128] = 14,417,920
    float* apart = ws + 40100000;                      // [112640][128]
    unsigned short* uvkb    = (unsigned short*)(ws + 54600000);   // [100k][384]
    unsigned short* h1b     = (unsigned short*)(ws + 73800000);   // [100k][128]
    unsigned short* hiddenb = (unsigned short*)(ws + 80200000);   // [100k][256]
    unsigned short* w3t   = (unsigned short*)(ws + 93000000);     // [128][128]
    unsigned short* w5t   = w3t + 16384;
    unsigned short* wcatt = w5t + 16384;               // [512][128]
    unsigned short* mw1t  = wcatt + 65536;             // [256][128]
    unsigned short* mw2t  = mw1t + 32768;              // [128][256]
    int* ibase    = (int*)(ws + 93100000);
    int* counts   = ibase;                             // [N]
    int* offsets  = ibase + 100000;                    // [N+1]
    int* cursor   = ibase + 200001;                    // [N]
    int* npieces  = ibase + 300001;                    // [N]
    int* ppos     = ibase + 400001;                    // [N+1]
    int* partials = ibase + 500102;                    // [128]
    int* edge_ord = ibase + 500230;                    // [E]
    int* src_ord  = edge_ord + N_EDGES;                // [E]
    int* dst_ord  = src_ord + N_EDGES;                 // [E]

    dim3 blk(256);
    hipMemsetAsync(counts, 0, N_NODES * sizeof(int), stream);

    hist_dst<<<N_EDGES / 256, blk, 0, stream>>>(dst, counts);
    scan_p1<<<98, blk, 0, stream>>>(counts, partials, N_NODES);
    scan_p2<<<1, 64, 0, stream>>>(partials, 98, offsets + N_NODES);
    scan_p3<<<98, blk, 0, stream>>>(counts, offsets, cursor, partials, N_NODES);
    scatter_edges<<<N_EDGES / 256, blk, 0, stream>>>(dst, src, cursor,
                                                     edge_ord, src_ord, dst_ord);
    calc_npieces<<<391, blk, 0, stream>>>(offsets, npieces);
    scan_p1<<<98, blk, 0, stream>>>(npieces, partials, N_NODES);
    scan_p2<<<1, 64, 0, stream>>>(partials, 98, ppos + N_NODES);
    scan_p3<<<98, blk, 0, stream>>>(npieces, ppos, (int*)nullptr, partials, N_NODES);

    prep_weights<<<576, blk, 0, stream>>>(W1, W2, W3, W4, W5, W6, mw1, mw2,
                                          w3t, w5t, wcatt, mw1t, mw2t);

    // u|v|k (bf16) and hw6 (f32) = h @ [W1|W2|W4|W6]  (A read f32, cvt in-reg)
    gemm_node<<<dim3(1563, 4), blk, 0, stream>>>(h, wcatt, uvkb, hw6f);

    edge_agg<<<N_EDGES / 64, blk, 0, stream>>>(e_ij, w3t, w5t, uvkb,
                                               edge_ord, src_ord, dst_ord,
                                               offsets, ppos, dpart, apart);

    node_finalize<<<N_NODES / 4, blk, 0, stream>>>(hw6f, uvkb, dpart, apart, ppos,
                                                   ln_g, ln_b, h1, h1b);

    // hidden = relu(h1 @ mw1)
    gemm_bf16<<<dim3(1563, 2), blk, 0, stream>>>(h1b, mw1t, N_NODES, 128, 256,
                                                 nullptr, nullptr, hiddenb, 1);
    // out = LN(hidden @ mw2 + h1)
    gemm_bf16_ln<<<1563, blk, 0, stream>>>(hiddenb, mw2t, N_NODES, 256,
                                           h1, ln_g, ln_b, out);
}

// Round 3
// 875.419 us; speedup vs baseline: 1.2816x; 1.0524x over previous
//
#include <hip/hip_runtime.h>
#include <hip/hip_bf16.h>

#define N_NODES 100000
#define N_EDGES 800000
#define EDGE_GRID 2500
#define EDGE_SLOTS 5

typedef __attribute__((ext_vector_type(8))) short short8v;   // 8 bf16 = 4 VGPRs
typedef __attribute__((ext_vector_type(4))) float f32x4;

__device__ __forceinline__ unsigned short f2bf(float f) {
    __hip_bfloat16 b = __float2bfloat16(f);
    return *(unsigned short*)&b;
}
__device__ __forceinline__ float bf2f(unsigned short u) {
    return __uint_as_float((unsigned)u << 16);
}
__device__ __forceinline__ unsigned pack2(float lo, float hi) {
    return (unsigned)f2bf(lo) | ((unsigned)f2bf(hi) << 16);
}

// async 16B global->LDS DMA (gfx950). LDS dest: wave-uniform base + lane*16.
__device__ __forceinline__ void gload_lds16(const void* g, void* l) {
    __builtin_amdgcn_global_load_lds(
        (const __attribute__((address_space(1))) unsigned int*)g,
        (__attribute__((address_space(3))) unsigned int*)l,
        16, 0, 0);
}

// ---------- CSR build ----------
__global__ __launch_bounds__(256) void hist_dst(
    const int* __restrict__ dst, int* __restrict__ counts)
{
    int e = blockIdx.x * 256 + threadIdx.x;
    if (e < N_EDGES) atomicAdd(&counts[dst[e]], 1);
}

__global__ __launch_bounds__(256) void scan_p1(
    const int* __restrict__ in, int* __restrict__ partials, int n)
{
    __shared__ int ws[4];
    int t = threadIdx.x, lane = t & 63, wv = t >> 6;
    int base = blockIdx.x * 1024;
    int s = 0;
#pragma unroll
    for (int i = 0; i < 4; ++i) {
        int idx = base + i * 256 + t;
        s += (idx < n) ? in[idx] : 0;
    }
#pragma unroll
    for (int off = 1; off < 64; off <<= 1) s += __shfl_xor(s, off);
    if (lane == 0) ws[wv] = s;
    __syncthreads();
    if (t == 0) partials[blockIdx.x] = ws[0] + ws[1] + ws[2] + ws[3];
}

__global__ __launch_bounds__(64) void scan_p2(
    int* __restrict__ partials, int nb, int* __restrict__ total_out)
{
    int lane = threadIdx.x;
    int carry = 0;
    for (int base = 0; base < nb; base += 64) {
        int idx = base + lane;
        int v = (idx < nb) ? partials[idx] : 0;
        int s = v;
#pragma unroll
        for (int off = 1; off < 64; off <<= 1) {
            int w = __shfl_up(s, off);
            if (lane >= off) s += w;
        }
        if (idx < nb) partials[idx] = s - v + carry;
        carry += __shfl(s, 63);
    }
    if (lane == 0) *total_out = carry;
}

__global__ __launch_bounds__(256) void scan_p3(
    const int* __restrict__ in, int* __restrict__ out, int* __restrict__ cursor,
    const int* __restrict__ partials, int n)
{
    __shared__ int ws[4];
    __shared__ int wpre[4];
    __shared__ int s_tot;
    int t = threadIdx.x, lane = t & 63, wv = t >> 6;
    int base = blockIdx.x * 1024;
    int carry = partials[blockIdx.x];
    for (int sub = 0; sub < 4; ++sub) {
        int idx = base + sub * 256 + t;
        int v = (idx < n) ? in[idx] : 0;
        int s = v;
#pragma unroll
        for (int off = 1; off < 64; off <<= 1) {
            int w = __shfl_up(s, off);
            if (lane >= off) s += w;
        }
        if (lane == 63) ws[wv] = s;
        __syncthreads();
        if (t == 0) {
            int a = 0;
#pragma unroll
            for (int i = 0; i < 4; ++i) { wpre[i] = a; a += ws[i]; }
            s_tot = a;
        }
        __syncthreads();
        int excl = s - v + wpre[wv] + carry;
        if (idx < n) { out[idx] = excl; if (cursor) cursor[idx] = excl; }
        carry += s_tot;
        __syncthreads();
    }
}

__global__ __launch_bounds__(256) void scatter_edges(
    const int* __restrict__ dst, const int* __restrict__ src,
    int* __restrict__ cursor,
    int* __restrict__ edge_ord, int* __restrict__ src_ord,
    int* __restrict__ dst_ord)
{
    int e = blockIdx.x * 256 + threadIdx.x;
    if (e < N_EDGES) {
        int d = dst[e];
        int pos = atomicAdd(&cursor[d], 1);
        edge_ord[pos] = e;
        src_ord[pos] = src[e];
        dst_ord[pos] = d;
    }
}

// npieces[n] = number of 64-slot blocks node n's slot range touches
__global__ __launch_bounds__(256) void calc_npieces(
    const int* __restrict__ offsets, int* __restrict__ npieces)
{
    int n = blockIdx.x * 256 + threadIdx.x;
    if (n < N_NODES) {
        int b = offsets[n], e = offsets[n + 1];
        npieces[n] = (e > b) ? (((e - 1) >> 6) - (b >> 6) + 1) : 0;
    }
}

// ---------- fused weight prep: w3t,w5t | wcatt | mw1t,mw2t ----------
__global__ __launch_bounds__(256) void prep_weights(
    const float* __restrict__ W1, const float* __restrict__ W2,
    const float* __restrict__ W3, const float* __restrict__ W4,
    const float* __restrict__ W5, const float* __restrict__ W6,
    const float* __restrict__ mw1, const float* __restrict__ mw2,
    unsigned short* __restrict__ w3t, unsigned short* __restrict__ w5t,
    unsigned short* __restrict__ wcatt,
    unsigned short* __restrict__ mw1t, unsigned short* __restrict__ mw2t)
{
    int bid = blockIdx.x;
    if (bid < 64) {
        int t = bid * 256 + threadIdx.x;          // 0..16383
        int r = t >> 7, c = t & 127;
        w3t[c * 128 + r] = f2bf(W3[t]);
        w5t[c * 128 + r] = f2bf(W5[t]);
    } else if (bid < 320) {
        int t = (bid - 64) * 256 + threadIdx.x;   // 0..65535
        int n = t >> 7, k = t & 127;
        const float* Wm = (n < 128) ? W1 : (n < 256) ? W2 : (n < 384) ? W4 : W6;
        wcatt[t] = f2bf(Wm[k * 128 + (n & 127)]);
    } else {
        int t = (bid - 320) * 256 + threadIdx.x;  // 0..65535
        if (t < 32768) {
            int n = t >> 7, k = t & 127;
            mw1t[t] = f2bf(mw1[k * 256 + n]);
        } else {
            int s = t - 32768;
            int n = s >> 8, k = s & 255;
            mw2t[s] = f2bf(mw2[k * 128 + n]);
        }
    }
}

// ---------- node GEMM: [u|v|k] bf16 + hw6 f32 = h(f32) @ [W1|W2|W4|W6] ----------
__global__ __launch_bounds__(256) void gemm_node(
    const float* __restrict__ A, const unsigned short* __restrict__ Bt,
    unsigned short* __restrict__ uvkb, float* __restrict__ hw6f)
{
    const int t = threadIdx.x;
    const int lane = t & 63, wv = t >> 6;
    const int l15 = lane & 15, kg = lane >> 4;
    const int m0 = blockIdx.x * 64;
    const int n0 = blockIdx.y * 128;
    const int M = N_NODES, K = 128;

    int arow = m0 + wv * 16 + l15;
    int arow_c = arow < M ? arow : M - 1;
    const float* ap = A + (size_t)arow_c * K + kg * 8;

    f32x4 acc[8];
#pragma unroll
    for (int nt = 0; nt < 8; ++nt) acc[nt] = (f32x4){0.f, 0.f, 0.f, 0.f};

    for (int ko = 0; ko < K; ko += 32) {
        float4 f0 = *(const float4*)(ap + ko);
        float4 f1 = *(const float4*)(ap + ko + 4);
        short8v af;
        af[0] = (short)f2bf(f0.x); af[1] = (short)f2bf(f0.y);
        af[2] = (short)f2bf(f0.z); af[3] = (short)f2bf(f0.w);
        af[4] = (short)f2bf(f1.x); af[5] = (short)f2bf(f1.y);
        af[6] = (short)f2bf(f1.z); af[7] = (short)f2bf(f1.w);
#pragma unroll
        for (int nt = 0; nt < 8; ++nt) {
            short8v bf = *(const short8v*)(Bt + (size_t)(n0 + nt * 16 + l15) * K + ko + kg * 8);
            acc[nt] = __builtin_amdgcn_mfma_f32_16x16x32_bf16(af, bf, acc[nt], 0, 0, 0);
        }
    }
#pragma unroll
    for (int nt = 0; nt < 8; ++nt) {
#pragma unroll
        for (int r = 0; r < 4; ++r) {
            int row = m0 + wv * 16 + kg * 4 + r;
            if (row < M) {
                int col = n0 + nt * 16 + l15;
                float vfl = acc[nt][r];
                if (n0 < 384) uvkb[(size_t)row * 384 + col] = f2bf(vfl);
                else          hw6f[(size_t)row * 128 + col - 384] = vfl;
            }
        }
    }
}

// ---------- generic bf16 MFMA GEMM (MLP hidden) ----------
__global__ __launch_bounds__(256) void gemm_bf16(
    const unsigned short* __restrict__ A, const unsigned short* __restrict__ Bt,
    int M, int K, int Nc,
    const float* __restrict__ res, float* __restrict__ Cf,
    unsigned short* __restrict__ Cb, int do_relu)
{
    const int t = threadIdx.x;
    const int lane = t & 63, wv = t >> 6;
    const int l15 = lane & 15, kg = lane >> 4;
    const int m0 = blockIdx.x * 64;
    const int n0 = blockIdx.y * 128;

    int arow = m0 + wv * 16 + l15;
    int arow_c = arow < M ? arow : M - 1;
    const unsigned short* ap = A + (size_t)arow_c * K + kg * 8;

    f32x4 acc[8];
#pragma unroll
    for (int nt = 0; nt < 8; ++nt) acc[nt] = (f32x4){0.f, 0.f, 0.f, 0.f};

    for (int ko = 0; ko < K; ko += 32) {
        short8v af = *(const short8v*)(ap + ko);
#pragma unroll
        for (int nt = 0; nt < 8; ++nt) {
            short8v bf = *(const short8v*)(Bt + (size_t)(n0 + nt * 16 + l15) * K + ko + kg * 8);
            acc[nt] = __builtin_amdgcn_mfma_f32_16x16x32_bf16(af, bf, acc[nt], 0, 0, 0);
        }
    }
#pragma unroll
    for (int nt = 0; nt < 8; ++nt) {
#pragma unroll
        for (int r = 0; r < 4; ++r) {
            int row = m0 + wv * 16 + kg * 4 + r;
            if (row < M) {
                int col = n0 + nt * 16 + l15;
                float vfl = acc[nt][r];
                if (res) vfl += res[(size_t)row * Nc + col];
                if (do_relu) vfl = fmaxf(vfl, 0.f);
                if (Cf) Cf[(size_t)row * Nc + col] = vfl;
                else    Cb[(size_t)row * Nc + col] = f2bf(vfl);
            }
        }
    }
}

// ---------- mw2 GEMM + residual + LayerNorm fused (Nc = 128) ----------
__global__ __launch_bounds__(256) void gemm_bf16_ln(
    const unsigned short* __restrict__ A, const unsigned short* __restrict__ Bt,
    int M, int K, const float* __restrict__ res,
    const float* __restrict__ gamma, const float* __restrict__ beta,
    float* __restrict__ out)
{
    const int t = threadIdx.x;
    const int lane = t & 63, wv = t >> 6;
    const int l15 = lane & 15, kg = lane >> 4;
    const int m0 = blockIdx.x * 64;

    int arow = m0 + wv * 16 + l15;
    int arow_c = arow < M ? arow : M - 1;
    const unsigned short* ap = A + (size_t)arow_c * K + kg * 8;

    f32x4 acc[8];
#pragma unroll
    for (int nt = 0; nt < 8; ++nt) acc[nt] = (f32x4){0.f, 0.f, 0.f, 0.f};

    for (int ko = 0; ko < K; ko += 32) {
        short8v af = *(const short8v*)(ap + ko);
#pragma unroll
        for (int nt = 0; nt < 8; ++nt) {
            short8v bf = *(const short8v*)(Bt + (size_t)(nt * 16 + l15) * K + ko + kg * 8);
            acc[nt] = __builtin_amdgcn_mfma_f32_16x16x32_bf16(af, bf, acc[nt], 0, 0, 0);
        }
    }

    float gv[8], bv[8];
#pragma unroll
    for (int nt = 0; nt < 8; ++nt) {
        gv[nt] = gamma[nt * 16 + l15];
        bv[nt] = beta[nt * 16 + l15];
    }

#pragma unroll
    for (int r = 0; r < 4; ++r) {
        int row = m0 + wv * 16 + kg * 4 + r;
        int rc = row < M ? row : M - 1;
        float x[8];
        float s = 0.f;
#pragma unroll
        for (int nt = 0; nt < 8; ++nt) {
            x[nt] = acc[nt][r] + res[(size_t)rc * 128 + nt * 16 + l15];
            s += x[nt];
        }
#pragma unroll
        for (int off = 1; off < 16; off <<= 1) s += __shfl_xor(s, off);
        float mu = s * (1.f / 128.f);
        float ss = 0.f;
#pragma unroll
        for (int nt = 0; nt < 8; ++nt) {
            float d = x[nt] - mu;
            ss += d * d;
        }
#pragma unroll
        for (int off = 1; off < 16; off <<= 1) ss += __shfl_xor(ss, off);
        float rsv = rsqrtf(ss * (1.f / 128.f) + 1e-5f);
        if (row < M) {
#pragma unroll
            for (int nt = 0; nt < 8; ++nt)
                out[(size_t)row * 128 + nt * 16 + l15] =
                    (x[nt] - mu) * rsv * gv[nt] + bv[nt];
        }
    }
}

// ---------- fused edge pass + in-register segmented aggregation ----------
// v16: persistent blocks (EDGE_GRID), EDGE_SLOTS slots each, double-buffered
// f32 e-tile staged via ASYNC global_load_lds (no VGPR round-trip, no cvt at
// stage). Stage(it+1) issued at top of compute(it); the single end-of-slot
// __syncthreads (compiler drains vmcnt) retires it -- loads have the whole
// compute phase (~HBM latency x several) to land. LDS layout linear (DMA
// requirement); bank conflicts handled by pre-swizzled global source +
// matching XOR on the read side (chunk j of row stored at j^(row&7)).
// Fused K-pass feeds both W3 and W5 MFMAs from one fragment (e read once).
// Meta triple-buffered, produced two slots ahead by wave 0.
__global__ __launch_bounds__(256) void edge_agg(
    const float* __restrict__ e_ij,
    const unsigned short* __restrict__ w3t, const unsigned short* __restrict__ w5t,
    const unsigned short* __restrict__ uvkb,
    const int* __restrict__ edge_ord, const int* __restrict__ src_ord,
    const int* __restrict__ dst_ord,
    const int* __restrict__ offsets, const int* __restrict__ ppos,
    float* __restrict__ dpart, float* __restrict__ apart)
{
    __shared__ __align__(16) float e_s[2][64 * 128];   // 2 x 32 KB f32
    __shared__ int s_eid[3][64], s_src[3][64], s_dst[3][64];
    __shared__ int s_sb[3][64], s_se[3][64], s_pi[3][64];
    __shared__ int s_nseg[3];

    const int t  = threadIdx.x;
    const int lane = t & 63, wv = t >> 6;
    const int l15 = lane & 15, kg = lane >> 4;
    const int cb = wv * 32 + 2 * l15;              // this lane's col pair
    const float inv = 0.17677669529663687f;        // 1/sqrt(32)
    const int b0 = blockIdx.x;
    const int sx = l15 & 7;                        // read-side XOR key (= row&7)

    // ---- prologue: meta for slots 0,1 ----
    if (t < 64) {
        for (int j = 0; j < 2; ++j) {
            int slot = b0 + j * EDGE_GRID;
            int e0 = slot * 64;
            int eid = edge_ord[e0 + t];
            int sv  = src_ord[e0 + t];
            int d   = dst_ord[e0 + t];
            s_eid[j][t] = eid; s_src[j][t] = sv; s_dst[j][t] = d;
            int dprev = __shfl_up(d, 1);
            bool bnd = (t == 0) || (d != dprev);
            unsigned long long mask = __ballot(bnd);
            int sid = __popcll(mask & ((1ull << t) - 1ull));
            if (bnd) {
                s_sb[j][sid] = t;
                s_pi[j][sid] = ppos[d] + slot - (offsets[d] >> 6);
                if (t > 0) s_se[j][sid - 1] = t;
            }
            if (t == 63) {
                int ns = __popcll(mask);
                s_se[j][ns - 1] = 64;
                s_nseg[j] = ns;
            }
        }
    }
    __syncthreads();

    // stage(slot0 -> buf0): 2048 chunks of 16B; thread t covers chunk i*256+t.
    // LDS chunk (row, j) receives global chunk j^(row&7) of row eid[row].
#pragma unroll
    for (int i = 0; i < 8; ++i) {
        int c = i * 256 + t;
        int row = c >> 5, j = c & 31;
        int js = j ^ (row & 7);
        const float* g = e_ij + (size_t)s_eid[0][row] * 128 + js * 4;
        void* l = (void*)((char*)(&e_s[0][0]) + (size_t)i * 4096 + (size_t)wv * 1024);
        gload_lds16(g, l);
    }
    __syncthreads();   // drains vmcnt: slot0 staged (prologue-only serialization)

    for (int it = 0; it < EDGE_SLOTS; ++it) {
        const int cur = it & 1;
        const int mi  = it % 3;
        const int mi1 = (it + 1) % 3;
        const int mi2 = (it + 2) % 3;

        // ---- top: async stage(slot it+1) into the other buffer ----
        if (it < EDGE_SLOTS - 1) {
#pragma unroll
            for (int i = 0; i < 8; ++i) {
                int c = i * 256 + t;
                int row = c >> 5, j = c & 31;
                int js = j ^ (row & 7);
                const float* g = e_ij + (size_t)s_eid[mi1][row] * 128 + js * 4;
                void* l = (void*)((char*)(&e_s[cur ^ 1][0]) + (size_t)i * 4096 + (size_t)wv * 1024);
                gload_lds16(g, l);
            }
        }
        // wave0: issue meta loads for slot it+2
        int m_eid = 0, m_src = 0, m_dst = 0;
        if (t < 64 && it < EDGE_SLOTS - 2) {
            int e0 = (b0 + (it + 2) * EDGE_GRID) * 64;
            m_eid = edge_ord[e0 + t];
            m_src = src_ord[e0 + t];
            m_dst = dst_ord[e0 + t];
        }

        const int nseg = __builtin_amdgcn_readfirstlane(s_nseg[mi]);
        const float* es = &e_s[cur][0];

        // ---- fused K-pass: a3 = e@W3 cols, a5 = e@W5 cols (same A frags) ----
        f32x4 a3[4][2], a5[4][2];
#pragma unroll
        for (int m = 0; m < 4; ++m) {
            a3[m][0] = (f32x4){0.f, 0.f, 0.f, 0.f};
            a3[m][1] = (f32x4){0.f, 0.f, 0.f, 0.f};
            a5[m][0] = (f32x4){0.f, 0.f, 0.f, 0.f};
            a5[m][1] = (f32x4){0.f, 0.f, 0.f, 0.f};
        }
        {
            const unsigned short* b3p0 = w3t + (size_t)(cb + 0) * 128 + kg * 8;
            const unsigned short* b3p1 = w3t + (size_t)(cb + 1) * 128 + kg * 8;
            const unsigned short* b5p0 = w5t + (size_t)(cb + 0) * 128 + kg * 8;
            const unsigned short* b5p1 = w5t + (size_t)(cb + 1) * 128 + kg * 8;
#pragma unroll
            for (int kidx = 0; kidx < 4; ++kidx) {
                const int ko = kidx * 32;
                short8v b30 = *(const short8v*)(b3p0 + ko);
                short8v b31 = *(const short8v*)(b3p1 + ko);
                short8v b50 = *(const short8v*)(b5p0 + ko);
                short8v b51 = *(const short8v*)(b5p1 + ko);
                const int g0 = (ko >> 2) + kg * 2;   // even global chunk
#pragma unroll
                for (int m = 0; m < 4; ++m) {
                    const int row = m * 16 + l15;
                    const float* rp = es + (size_t)row * 128;
                    float4 f0 = *(const float4*)(rp + (((g0)     ^ sx) << 2));
                    float4 f1 = *(const float4*)(rp + (((g0 + 1) ^ sx) << 2));
                    short8v af;
                    af[0] = (short)f2bf(f0.x); af[1] = (short)f2bf(f0.y);
                    af[2] = (short)f2bf(f0.z); af[3] = (short)f2bf(f0.w);
                    af[4] = (short)f2bf(f1.x); af[5] = (short)f2bf(f1.y);
                    af[6] = (short)f2bf(f1.z); af[7] = (short)f2bf(f1.w);
                    a3[m][0] = __builtin_amdgcn_mfma_f32_16x16x32_bf16(af, b30, a3[m][0], 0, 0, 0);
                    a3[m][1] = __builtin_amdgcn_mfma_f32_16x16x32_bf16(af, b31, a3[m][1], 0, 0, 0);
                    a5[m][0] = __builtin_amdgcn_mfma_f32_16x16x32_bf16(af, b50, a5[m][0], 0, 0, 0);
                    a5[m][1] = __builtin_amdgcn_mfma_f32_16x16x32_bf16(af, b51, a5[m][1], 0, 0, 0);
                }
            }
        }

        // ---- epilogue: ex = exp(u*(v+x3)*inv) in place over a3; a5 *= ex ----
#pragma unroll
        for (int m = 0; m < 4; ++m) {
#pragma unroll
            for (int r = 0; r < 4; ++r) {
                int le = m * 16 + kg * 4 + r;
                int d  = s_dst[mi][le];
                int sv = s_src[mi][le];
                unsigned upk = *(const unsigned*)&uvkb[(size_t)sv * 384 + cb];
                unsigned vpk = *(const unsigned*)&uvkb[(size_t)d * 384 + 128 + cb];
                float u0 = bf2f((unsigned short)(upk & 0xffffu));
                float u1 = bf2f((unsigned short)(upk >> 16));
                float v0 = bf2f((unsigned short)(vpk & 0xffffu));
                float v1 = bf2f((unsigned short)(vpk >> 16));
                float at0 = u0 * (v0 + a3[m][0][r]) * inv;
                float at1 = u1 * (v1 + a3[m][1][r]) * inv;
                float ex0 = __expf(fminf(at0, 80.f));
                float ex1 = __expf(fminf(at1, 80.f));
                a3[m][0][r] = ex0;
                a3[m][1][r] = ex1;
                a5[m][0][r] = ex0 * a5[m][0][r];
                a5[m][1][r] = ex1 * a5[m][1][r];
            }
        }

        // ---- combined segmented reduce -> dpart, apart ----
        for (int sg = 0; sg < nseg; ++sg) {
            const int b  = __builtin_amdgcn_readfirstlane(s_sb[mi][sg]);
            const int e2 = __builtin_amdgcn_readfirstlane(s_se[mi][sg]);
            const int pi = __builtin_amdgcn_readfirstlane(s_pi[mi][sg]);
            float d0 = 0.f, d1 = 0.f, g0 = 0.f, g1 = 0.f;
#pragma unroll
            for (int m = 0; m < 4; ++m) {
                if (b < m * 16 + 16 && e2 > m * 16) {   // scalar branch: skip m-block
#pragma unroll
                    for (int r = 0; r < 4; ++r) {
                        int slot = m * 16 + kg * 4 + r;
                        bool in = (slot >= b) && (slot < e2);
                        d0 += in ? a3[m][0][r] : 0.f;
                        d1 += in ? a3[m][1][r] : 0.f;
                        g0 += in ? a5[m][0][r] : 0.f;
                        g1 += in ? a5[m][1][r] : 0.f;
                    }
                }
            }
            d0 += __shfl_xor(d0, 16); d0 += __shfl_xor(d0, 32);
            d1 += __shfl_xor(d1, 16); d1 += __shfl_xor(d1, 32);
            g0 += __shfl_xor(g0, 16); g0 += __shfl_xor(g0, 32);
            g1 += __shfl_xor(g1, 16); g1 += __shfl_xor(g1, 32);
            if (kg == 0) {
                *(float2*)&dpart[(size_t)pi * 128 + cb] = make_float2(d0, d1);
                *(float2*)&apart[(size_t)pi * 128 + cb] = make_float2(g0, g1);
            }
        }

        // ---- tail: wave0 ballots slot it+2 meta into meta[mi2] ----
        if (t < 64 && it < EDGE_SLOTS - 2) {
            int slot2 = b0 + (it + 2) * EDGE_GRID;
            s_eid[mi2][t] = m_eid; s_src[mi2][t] = m_src; s_dst[mi2][t] = m_dst;
            int dprev = __shfl_up(m_dst, 1);
            bool bnd = (t == 0) || (m_dst != dprev);
            unsigned long long mask = __ballot(bnd);
            int sid = __popcll(mask & ((1ull << t) - 1ull));
            if (bnd) {
                s_sb[mi2][sid] = t;
                s_pi[mi2][sid] = ppos[m_dst] + slot2 - (offsets[m_dst] >> 6);
                if (t > 0) s_se[mi2][sid - 1] = t;
            }
            if (t == 63) {
                int ns = __popcll(mask);
                s_se[mi2][ns - 1] = 64;
                s_nseg[mi2] = ns;
            }
        }
        // one barrier per slot: retires stage(it+1) (vmcnt drain) + meta(it+2)
        __syncthreads();
    }
}

// ---------- node finalize: sum pieces, h1 = LN(hw6 + k + agg/denom) ----------
__global__ __launch_bounds__(256) void node_finalize(
    const float* __restrict__ hw6f, const unsigned short* __restrict__ uvkb,
    const float* __restrict__ dpart, const float* __restrict__ apart,
    const int* __restrict__ ppos,
    const float* __restrict__ gamma, const float* __restrict__ beta,
    float* __restrict__ h1, unsigned short* __restrict__ h1b)
{
    int n = blockIdx.x * 4 + (threadIdx.x >> 6);
    int lane = threadIdx.x & 63;
    int p0 = ppos[n], p1 = ppos[n + 1];
    float de0 = 0.f, de1 = 0.f, g0 = 0.f, g1 = 0.f;
    for (int j = p0; j < p1; ++j) {
        float2 dv = *(const float2*)&dpart[(size_t)j * 128 + lane * 2];
        float2 av = *(const float2*)&apart[(size_t)j * 128 + lane * 2];
        de0 += dv.x; de1 += dv.y;
        g0  += av.x; g1  += av.y;
    }
    unsigned kpk = *(const unsigned*)&uvkb[(size_t)n * 384 + 256 + lane * 2];
    float k0 = bf2f((unsigned short)(kpk & 0xffffu));
    float k1 = bf2f((unsigned short)(kpk >> 16));
    float2 hw = *(const float2*)&hw6f[(size_t)n * 128 + lane * 2];
    float x0 = hw.x + (de0 > 0.f ? k0 + g0 / de0 : 0.f);
    float x1 = hw.y + (de1 > 0.f ? k1 + g1 / de1 : 0.f);
    float s = x0 + x1;
#pragma unroll
    for (int off = 1; off < 64; off <<= 1) s += __shfl_xor(s, off);
    float mu = s * (1.f / 128.f);
    float d0 = x0 - mu, d1 = x1 - mu;
    float ss = d0 * d0 + d1 * d1;
#pragma unroll
    for (int off = 1; off < 64; off <<= 1) ss += __shfl_xor(ss, off);
    float rs = rsqrtf(ss * (1.f / 128.f) + 1e-5f);
    float2 g = *(const float2*)&gamma[lane * 2];
    float2 b = *(const float2*)&beta[lane * 2];
    float o0 = d0 * rs * g.x + b.x;
    float o1 = d1 * rs * g.y + b.y;
    size_t base = (size_t)n * 128 + lane * 2;
    *(float2*)&h1[base] = make_float2(o0, o1);
    *(unsigned*)&h1b[base] = pack2(o0, o1);
}

extern "C" void kernel_launch(void* const* d_in, const int* in_sizes, int n_in,
                              void* d_out, int out_size, void* d_ws, size_t ws_size,
                              hipStream_t stream)
{
    const float* h    = (const float*)d_in[0];
    const float* e_ij = (const float*)d_in[1];
    const float* W1   = (const float*)d_in[2];
    const float* W2   = (const float*)d_in[3];
    const float* W3   = (const float*)d_in[4];
    const float* W4   = (const float*)d_in[5];
    const float* W5   = (const float*)d_in[6];
    const float* W6   = (const float*)d_in[7];
    const float* ln_g = (const float*)d_in[8];
    const float* ln_b = (const float*)d_in[9];
    const float* mw1  = (const float*)d_in[10];
    const float* mw2  = (const float*)d_in[11];
    const int*   src  = (const int*)d_in[12];
    const int*   dst  = (const int*)d_in[13];
    float* out = (float*)d_out;

    float* ws = (float*)d_ws;
    // layout (float offsets); P_max = 112640 pieces (N + E/64 rounded up)
    float* hw6f  = ws;                                 // [100k][128]
    float* h1    = ws + 12800000;                      // [100k][128]
    float* dpart = ws + 25600000;                      // [112640][128] = 14,417,920
    float* apart = ws + 40100000;                      // [112640][128]
    unsigned short* uvkb    = (unsigned short*)(ws + 54600000);   // [100k][384]
    unsigned short* h1b     = (unsigned short*)(ws + 73800000);   // [100k][128]
    unsigned short* hiddenb = (unsigned short*)(ws + 80200000);   // [100k][256]
    unsigned short* w3t   = (unsigned short*)(ws + 93000000);     // [128][128]
    unsigned short* w5t   = w3t + 16384;
    unsigned short* wcatt = w5t + 16384;               // [512][128]
    unsigned short* mw1t  = wcatt + 65536;             // [256][128]
    unsigned short* mw2t  = mw1t + 32768;              // [128][256]
    int* ibase    = (int*)(ws + 93100000);
    int* counts   = ibase;                             // [N]
    int* offsets  = ibase + 100000;                    // [N+1]
    int* cursor   = ibase + 200001;                    // [N]
    int* npieces  = ibase + 300001;                    // [N]
    int* ppos     = ibase + 400001;                    // [N+1]
    int* partials = ibase + 500102;                    // [128]
    int* edge_ord = ibase + 500230;                    // [E]
    int* src_ord  = edge_ord + N_EDGES;                // [E]
    int* dst_ord  = src_ord + N_EDGES;                 // [E]

    dim3 blk(256);
    hipMemsetAsync(counts, 0, N_NODES * sizeof(int), stream);

    hist_dst<<<N_EDGES / 256, blk, 0, stream>>>(dst, counts);
    scan_p1<<<98, blk, 0, stream>>>(counts, partials, N_NODES);
    scan_p2<<<1, 64, 0, stream>>>(partials, 98, offsets + N_NODES);
    scan_p3<<<98, blk, 0, stream>>>(counts, offsets, cursor, partials, N_NODES);
    scatter_edges<<<N_EDGES / 256, blk, 0, stream>>>(dst, src, cursor,
                                                     edge_ord, src_ord, dst_ord);
    calc_npieces<<<391, blk, 0, stream>>>(offsets, npieces);
    scan_p1<<<98, blk, 0, stream>>>(npieces, partials, N_NODES);
    scan_p2<<<1, 64, 0, stream>>>(partials, 98, ppos + N_NODES);
    scan_p3<<<98, blk, 0, stream>>>(npieces, ppos, (int*)nullptr, partials, N_NODES);

    prep_weights<<<576, blk, 0, stream>>>(W1, W2, W3, W4, W5, W6, mw1, mw2,
                                          w3t, w5t, wcatt, mw1t, mw2t);

    // u|v|k (bf16) and hw6 (f32) = h @ [W1|W2|W4|W6]  (A read f32, cvt in-reg)
    gemm_node<<<dim3(1563, 4), blk, 0, stream>>>(h, wcatt, uvkb, hw6f);

    edge_agg<<<EDGE_GRID, blk, 0, stream>>>(e_ij, w3t, w5t, uvkb,
                                            edge_ord, src_ord, dst_ord,
                                            offsets, ppos, dpart, apart);

    node_finalize<<<N_NODES / 4, blk, 0, stream>>>(hw6f, uvkb, dpart, apart, ppos,
                                                   ln_g, ln_b, h1, h1b);

    // hidden = relu(h1 @ mw1)
    gemm_bf16<<<dim3(1563, 2), blk, 0, stream>>>(h1b, mw1t, N_NODES, 128, 256,
                                                 nullptr, nullptr, hiddenb, 1);
    // out = LN(hidden @ mw2 + h1)
    gemm_bf16_ln<<<1563, blk, 0, stream>>>(hiddenb, mw2t, N_NODES, 256,
                                           h1, ln_g, ln_b, out);
}

// Round 4
// 836.769 us; speedup vs baseline: 1.3408x; 1.0462x over previous
//
#include <hip/hip_runtime.h>
#include <hip/hip_bf16.h>

#define N_NODES 100000
#define N_EDGES 800000
#define EDGE_GRID 2500
#define EDGE_SLOTS 5

typedef __attribute__((ext_vector_type(8))) short short8v;   // 8 bf16 = 4 VGPRs
typedef __attribute__((ext_vector_type(4))) float f32x4;

__device__ __forceinline__ unsigned short f2bf(float f) {
    __hip_bfloat16 b = __float2bfloat16(f);
    return *(unsigned short*)&b;
}
__device__ __forceinline__ float bf2f(unsigned short u) {
    return __uint_as_float((unsigned)u << 16);
}
__device__ __forceinline__ unsigned pack2(float lo, float hi) {
    return (unsigned)f2bf(lo) | ((unsigned)f2bf(hi) << 16);
}

// async 16B global->LDS DMA (gfx950). LDS dest: wave-uniform base + lane*16.
__device__ __forceinline__ void gload_lds16(const void* g, void* l) {
    __builtin_amdgcn_global_load_lds(
        (const __attribute__((address_space(1))) unsigned int*)g,
        (__attribute__((address_space(3))) unsigned int*)l,
        16, 0, 0);
}

// ---------- CSR build ----------
__global__ __launch_bounds__(256) void hist_dst(
    const int* __restrict__ dst, int* __restrict__ counts)
{
    int e = blockIdx.x * 256 + threadIdx.x;
    if (e < N_EDGES) atomicAdd(&counts[dst[e]], 1);
}

__global__ __launch_bounds__(256) void scan_p1(
    const int* __restrict__ in, int* __restrict__ partials, int n)
{
    __shared__ int ws[4];
    int t = threadIdx.x, lane = t & 63, wv = t >> 6;
    int base = blockIdx.x * 1024;
    int s = 0;
#pragma unroll
    for (int i = 0; i < 4; ++i) {
        int idx = base + i * 256 + t;
        s += (idx < n) ? in[idx] : 0;
    }
#pragma unroll
    for (int off = 1; off < 64; off <<= 1) s += __shfl_xor(s, off);
    if (lane == 0) ws[wv] = s;
    __syncthreads();
    if (t == 0) partials[blockIdx.x] = ws[0] + ws[1] + ws[2] + ws[3];
}

__global__ __launch_bounds__(64) void scan_p2(
    int* __restrict__ partials, int nb, int* __restrict__ total_out)
{
    int lane = threadIdx.x;
    int carry = 0;
    for (int base = 0; base < nb; base += 64) {
        int idx = base + lane;
        int v = (idx < nb) ? partials[idx] : 0;
        int s = v;
#pragma unroll
        for (int off = 1; off < 64; off <<= 1) {
            int w = __shfl_up(s, off);
            if (lane >= off) s += w;
        }
        if (idx < nb) partials[idx] = s - v + carry;
        carry += __shfl(s, 63);
    }
    if (lane == 0) *total_out = carry;
}

__global__ __launch_bounds__(256) void scan_p3(
    const int* __restrict__ in, int* __restrict__ out, int* __restrict__ cursor,
    const int* __restrict__ partials, int n)
{
    __shared__ int ws[4];
    __shared__ int wpre[4];
    __shared__ int s_tot;
    int t = threadIdx.x, lane = t & 63, wv = t >> 6;
    int base = blockIdx.x * 1024;
    int carry = partials[blockIdx.x];
    for (int sub = 0; sub < 4; ++sub) {
        int idx = base + sub * 256 + t;
        int v = (idx < n) ? in[idx] : 0;
        int s = v;
#pragma unroll
        for (int off = 1; off < 64; off <<= 1) {
            int w = __shfl_up(s, off);
            if (lane >= off) s += w;
        }
        if (lane == 63) ws[wv] = s;
        __syncthreads();
        if (t == 0) {
            int a = 0;
#pragma unroll
            for (int i = 0; i < 4; ++i) { wpre[i] = a; a += ws[i]; }
            s_tot = a;
        }
        __syncthreads();
        int excl = s - v + wpre[wv] + carry;
        if (idx < n) { out[idx] = excl; if (cursor) cursor[idx] = excl; }
        carry += s_tot;
        __syncthreads();
    }
}

__global__ __launch_bounds__(256) void scatter_edges(
    const int* __restrict__ dst, const int* __restrict__ src,
    int* __restrict__ cursor,
    int* __restrict__ edge_ord, int* __restrict__ src_ord,
    int* __restrict__ dst_ord)
{
    int e = blockIdx.x * 256 + threadIdx.x;
    if (e < N_EDGES) {
        int d = dst[e];
        int pos = atomicAdd(&cursor[d], 1);
        edge_ord[pos] = e;
        src_ord[pos] = src[e];
        dst_ord[pos] = d;
    }
}

// npieces[n] = number of 64-slot blocks node n's slot range touches
__global__ __launch_bounds__(256) void calc_npieces(
    const int* __restrict__ offsets, int* __restrict__ npieces)
{
    int n = blockIdx.x * 256 + threadIdx.x;
    if (n < N_NODES) {
        int b = offsets[n], e = offsets[n + 1];
        npieces[n] = (e > b) ? (((e - 1) >> 6) - (b >> 6) + 1) : 0;
    }
}

// ---------- fused weight prep: w3t,w5t | wcatt | mw1t,mw2t ----------
__global__ __launch_bounds__(256) void prep_weights(
    const float* __restrict__ W1, const float* __restrict__ W2,
    const float* __restrict__ W3, const float* __restrict__ W4,
    const float* __restrict__ W5, const float* __restrict__ W6,
    const float* __restrict__ mw1, const float* __restrict__ mw2,
    unsigned short* __restrict__ w3t, unsigned short* __restrict__ w5t,
    unsigned short* __restrict__ wcatt,
    unsigned short* __restrict__ mw1t, unsigned short* __restrict__ mw2t)
{
    int bid = blockIdx.x;
    if (bid < 64) {
        int t = bid * 256 + threadIdx.x;          // 0..16383
        int r = t >> 7, c = t & 127;
        w3t[c * 128 + r] = f2bf(W3[t]);
        w5t[c * 128 + r] = f2bf(W5[t]);
    } else if (bid < 320) {
        int t = (bid - 64) * 256 + threadIdx.x;   // 0..65535
        int n = t >> 7, k = t & 127;
        const float* Wm = (n < 128) ? W1 : (n < 256) ? W2 : (n < 384) ? W4 : W6;
        wcatt[t] = f2bf(Wm[k * 128 + (n & 127)]);
    } else {
        int t = (bid - 320) * 256 + threadIdx.x;  // 0..65535
        if (t < 32768) {
            int n = t >> 7, k = t & 127;
            mw1t[t] = f2bf(mw1[k * 256 + n]);
        } else {
            int s = t - 32768;
            int n = s >> 8, k = s & 255;
            mw2t[s] = f2bf(mw2[k * 128 + n]);
        }
    }
}

// ---------- node GEMM: [u|v|k] bf16 + hw6 f32 = h(f32) @ [W1|W2|W4|W6] ----------
__global__ __launch_bounds__(256) void gemm_node(
    const float* __restrict__ A, const unsigned short* __restrict__ Bt,
    unsigned short* __restrict__ uvkb, float* __restrict__ hw6f)
{
    const int t = threadIdx.x;
    const int lane = t & 63, wv = t >> 6;
    const int l15 = lane & 15, kg = lane >> 4;
    const int m0 = blockIdx.x * 64;
    const int n0 = blockIdx.y * 128;
    const int M = N_NODES, K = 128;

    int arow = m0 + wv * 16 + l15;
    int arow_c = arow < M ? arow : M - 1;
    const float* ap = A + (size_t)arow_c * K + kg * 8;

    f32x4 acc[8];
#pragma unroll
    for (int nt = 0; nt < 8; ++nt) acc[nt] = (f32x4){0.f, 0.f, 0.f, 0.f};

    for (int ko = 0; ko < K; ko += 32) {
        float4 f0 = *(const float4*)(ap + ko);
        float4 f1 = *(const float4*)(ap + ko + 4);
        short8v af;
        af[0] = (short)f2bf(f0.x); af[1] = (short)f2bf(f0.y);
        af[2] = (short)f2bf(f0.z); af[3] = (short)f2bf(f0.w);
        af[4] = (short)f2bf(f1.x); af[5] = (short)f2bf(f1.y);
        af[6] = (short)f2bf(f1.z); af[7] = (short)f2bf(f1.w);
#pragma unroll
        for (int nt = 0; nt < 8; ++nt) {
            short8v bf = *(const short8v*)(Bt + (size_t)(n0 + nt * 16 + l15) * K + ko + kg * 8);
            acc[nt] = __builtin_amdgcn_mfma_f32_16x16x32_bf16(af, bf, acc[nt], 0, 0, 0);
        }
    }
#pragma unroll
    for (int nt = 0; nt < 8; ++nt) {
#pragma unroll
        for (int r = 0; r < 4; ++r) {
            int row = m0 + wv * 16 + kg * 4 + r;
            if (row < M) {
                int col = n0 + nt * 16 + l15;
                float vfl = acc[nt][r];
                if (n0 < 384) uvkb[(size_t)row * 384 + col] = f2bf(vfl);
                else          hw6f[(size_t)row * 128 + col - 384] = vfl;
            }
        }
    }
}

// ---------- generic bf16 MFMA GEMM (MLP hidden) ----------
__global__ __launch_bounds__(256) void gemm_bf16(
    const unsigned short* __restrict__ A, const unsigned short* __restrict__ Bt,
    int M, int K, int Nc,
    const float* __restrict__ res, float* __restrict__ Cf,
    unsigned short* __restrict__ Cb, int do_relu)
{
    const int t = threadIdx.x;
    const int lane = t & 63, wv = t >> 6;
    const int l15 = lane & 15, kg = lane >> 4;
    const int m0 = blockIdx.x * 64;
    const int n0 = blockIdx.y * 128;

    int arow = m0 + wv * 16 + l15;
    int arow_c = arow < M ? arow : M - 1;
    const unsigned short* ap = A + (size_t)arow_c * K + kg * 8;

    f32x4 acc[8];
#pragma unroll
    for (int nt = 0; nt < 8; ++nt) acc[nt] = (f32x4){0.f, 0.f, 0.f, 0.f};

    for (int ko = 0; ko < K; ko += 32) {
        short8v af = *(const short8v*)(ap + ko);
#pragma unroll
        for (int nt = 0; nt < 8; ++nt) {
            short8v bf = *(const short8v*)(Bt + (size_t)(n0 + nt * 16 + l15) * K + ko + kg * 8);
            acc[nt] = __builtin_amdgcn_mfma_f32_16x16x32_bf16(af, bf, acc[nt], 0, 0, 0);
        }
    }
#pragma unroll
    for (int nt = 0; nt < 8; ++nt) {
#pragma unroll
        for (int r = 0; r < 4; ++r) {
            int row = m0 + wv * 16 + kg * 4 + r;
            if (row < M) {
                int col = n0 + nt * 16 + l15;
                float vfl = acc[nt][r];
                if (res) vfl += res[(size_t)row * Nc + col];
                if (do_relu) vfl = fmaxf(vfl, 0.f);
                if (Cf) Cf[(size_t)row * Nc + col] = vfl;
                else    Cb[(size_t)row * Nc + col] = f2bf(vfl);
            }
        }
    }
}

// ---------- mw2 GEMM + residual + LayerNorm fused (Nc = 128) ----------
__global__ __launch_bounds__(256) void gemm_bf16_ln(
    const unsigned short* __restrict__ A, const unsigned short* __restrict__ Bt,
    int M, int K, const float* __restrict__ res,
    const float* __restrict__ gamma, const float* __restrict__ beta,
    float* __restrict__ out)
{
    const int t = threadIdx.x;
    const int lane = t & 63, wv = t >> 6;
    const int l15 = lane & 15, kg = lane >> 4;
    const int m0 = blockIdx.x * 64;

    int arow = m0 + wv * 16 + l15;
    int arow_c = arow < M ? arow : M - 1;
    const unsigned short* ap = A + (size_t)arow_c * K + kg * 8;

    f32x4 acc[8];
#pragma unroll
    for (int nt = 0; nt < 8; ++nt) acc[nt] = (f32x4){0.f, 0.f, 0.f, 0.f};

    for (int ko = 0; ko < K; ko += 32) {
        short8v af = *(const short8v*)(ap + ko);
#pragma unroll
        for (int nt = 0; nt < 8; ++nt) {
            short8v bf = *(const short8v*)(Bt + (size_t)(nt * 16 + l15) * K + ko + kg * 8);
            acc[nt] = __builtin_amdgcn_mfma_f32_16x16x32_bf16(af, bf, acc[nt], 0, 0, 0);
        }
    }

    float gv[8], bv[8];
#pragma unroll
    for (int nt = 0; nt < 8; ++nt) {
        gv[nt] = gamma[nt * 16 + l15];
        bv[nt] = beta[nt * 16 + l15];
    }

#pragma unroll
    for (int r = 0; r < 4; ++r) {
        int row = m0 + wv * 16 + kg * 4 + r;
        int rc = row < M ? row : M - 1;
        float x[8];
        float s = 0.f;
#pragma unroll
        for (int nt = 0; nt < 8; ++nt) {
            x[nt] = acc[nt][r] + res[(size_t)rc * 128 + nt * 16 + l15];
            s += x[nt];
        }
#pragma unroll
        for (int off = 1; off < 16; off <<= 1) s += __shfl_xor(s, off);
        float mu = s * (1.f / 128.f);
        float ss = 0.f;
#pragma unroll
        for (int nt = 0; nt < 8; ++nt) {
            float d = x[nt] - mu;
            ss += d * d;
        }
#pragma unroll
        for (int off = 1; off < 16; off <<= 1) ss += __shfl_xor(ss, off);
        float rsv = rsqrtf(ss * (1.f / 128.f) + 1e-5f);
        if (row < M) {
#pragma unroll
            for (int nt = 0; nt < 8; ++nt)
                out[(size_t)row * 128 + nt * 16 + l15] =
                    (x[nt] - mu) * rsv * gv[nt] + bv[nt];
        }
    }
}

// ---------- fused edge pass + in-register segmented aggregation ----------
// v17: v16 + vmcnt-FIFO-aware VMEM issue order per slot:
//   (1) uvkb u/v gathers for CURRENT slot -> 32 regs  (OLDEST)
//   (2) wave0 meta loads for slot it+2
//   (3) async DMA stage of slot it+1                  (YOUNGEST)
//   sched_barrier(0) pins this order against compiler sinking.
// Consequence: the epilogue's wait on uvkb (oldest) retires WITHOUT draining
// the younger stage DMAs; DMAs stay in flight across MFMA+epilogue+reduce and
// are drained only at the single end-of-slot barrier. (v16 issued the gathers
// after the DMAs, so the first gather-use force-drained the whole stage --
// measured 9.8us/slot vs the ~2.6us BW floor.)
__global__ __launch_bounds__(256) void edge_agg(
    const float* __restrict__ e_ij,
    const unsigned short* __restrict__ w3t, const unsigned short* __restrict__ w5t,
    const unsigned short* __restrict__ uvkb,
    const int* __restrict__ edge_ord, const int* __restrict__ src_ord,
    const int* __restrict__ dst_ord,
    const int* __restrict__ offsets, const int* __restrict__ ppos,
    float* __restrict__ dpart, float* __restrict__ apart)
{
    __shared__ __align__(16) float e_s[2][64 * 128];   // 2 x 32 KB f32
    __shared__ int s_eid[3][64], s_src[3][64], s_dst[3][64];
    __shared__ int s_sb[3][64], s_se[3][64], s_pi[3][64];
    __shared__ int s_nseg[3];

    const int t  = threadIdx.x;
    const int lane = t & 63, wv = t >> 6;
    const int l15 = lane & 15, kg = lane >> 4;
    const int cb = wv * 32 + 2 * l15;              // this lane's col pair
    const float inv = 0.17677669529663687f;        // 1/sqrt(32)
    const int b0 = blockIdx.x;
    const int sx = l15 & 7;                        // read-side XOR key (= row&7)

    // ---- prologue: meta for slots 0,1 ----
    if (t < 64) {
        for (int j = 0; j < 2; ++j) {
            int slot = b0 + j * EDGE_GRID;
            int e0 = slot * 64;
            int eid = edge_ord[e0 + t];
            int sv  = src_ord[e0 + t];
            int d   = dst_ord[e0 + t];
            s_eid[j][t] = eid; s_src[j][t] = sv; s_dst[j][t] = d;
            int dprev = __shfl_up(d, 1);
            bool bnd = (t == 0) || (d != dprev);
            unsigned long long mask = __ballot(bnd);
            int sid = __popcll(mask & ((1ull << t) - 1ull));
            if (bnd) {
                s_sb[j][sid] = t;
                s_pi[j][sid] = ppos[d] + slot - (offsets[d] >> 6);
                if (t > 0) s_se[j][sid - 1] = t;
            }
            if (t == 63) {
                int ns = __popcll(mask);
                s_se[j][ns - 1] = 64;
                s_nseg[j] = ns;
            }
        }
    }
    __syncthreads();

    // stage(slot0 -> buf0): 2048 chunks of 16B; thread t covers chunk i*256+t.
    // LDS chunk (row, j) receives global chunk j^(row&7) of row eid[row].
#pragma unroll
    for (int i = 0; i < 8; ++i) {
        int c = i * 256 + t;
        int row = c >> 5, j = c & 31;
        int js = j ^ (row & 7);
        const float* g = e_ij + (size_t)s_eid[0][row] * 128 + js * 4;
        void* l = (void*)((char*)(&e_s[0][0]) + (size_t)i * 4096 + (size_t)wv * 1024);
        gload_lds16(g, l);
    }
    __syncthreads();   // drains vmcnt: slot0 staged (prologue-only serialization)

    for (int it = 0; it < EDGE_SLOTS; ++it) {
        const int cur = it & 1;
        const int mi  = it % 3;
        const int mi1 = (it + 1) % 3;
        const int mi2 = (it + 2) % 3;

        // ---- (1) OLDEST: uvkb u/v gathers for the CURRENT slot ----
        unsigned upk[4][4], vpk[4][4];
#pragma unroll
        for (int m = 0; m < 4; ++m) {
#pragma unroll
            for (int r = 0; r < 4; ++r) {
                int le = m * 16 + kg * 4 + r;
                int d  = s_dst[mi][le];
                int sv = s_src[mi][le];
                upk[m][r] = *(const unsigned*)&uvkb[(size_t)sv * 384 + cb];
                vpk[m][r] = *(const unsigned*)&uvkb[(size_t)d * 384 + 128 + cb];
            }
        }
        // ---- (2) wave0 meta loads for slot it+2 ----
        int m_eid = 0, m_src = 0, m_dst = 0;
        if (t < 64 && it < EDGE_SLOTS - 2) {
            int e0 = (b0 + (it + 2) * EDGE_GRID) * 64;
            m_eid = edge_ord[e0 + t];
            m_src = src_ord[e0 + t];
            m_dst = dst_ord[e0 + t];
        }
        // ---- (3) YOUNGEST: async DMA stage of slot it+1 ----
        if (it < EDGE_SLOTS - 1) {
#pragma unroll
            for (int i = 0; i < 8; ++i) {
                int c = i * 256 + t;
                int row = c >> 5, j = c & 31;
                int js = j ^ (row & 7);
                const float* g = e_ij + (size_t)s_eid[mi1][row] * 128 + js * 4;
                void* l = (void*)((char*)(&e_s[cur ^ 1][0]) + (size_t)i * 4096 + (size_t)wv * 1024);
                gload_lds16(g, l);
            }
        }
        __builtin_amdgcn_sched_barrier(0);   // pin VMEM issue order above

        const int nseg = __builtin_amdgcn_readfirstlane(s_nseg[mi]);
        const float* es = &e_s[cur][0];

        // ---- fused K-pass: a3 = e@W3 cols, a5 = e@W5 cols (same A frags) ----
        f32x4 a3[4][2], a5[4][2];
#pragma unroll
        for (int m = 0; m < 4; ++m) {
            a3[m][0] = (f32x4){0.f, 0.f, 0.f, 0.f};
            a3[m][1] = (f32x4){0.f, 0.f, 0.f, 0.f};
            a5[m][0] = (f32x4){0.f, 0.f, 0.f, 0.f};
            a5[m][1] = (f32x4){0.f, 0.f, 0.f, 0.f};
        }
        {
            const unsigned short* b3p0 = w3t + (size_t)(cb + 0) * 128 + kg * 8;
            const unsigned short* b3p1 = w3t + (size_t)(cb + 1) * 128 + kg * 8;
            const unsigned short* b5p0 = w5t + (size_t)(cb + 0) * 128 + kg * 8;
            const unsigned short* b5p1 = w5t + (size_t)(cb + 1) * 128 + kg * 8;
#pragma unroll
            for (int kidx = 0; kidx < 4; ++kidx) {
                const int ko = kidx * 32;
                short8v b30 = *(const short8v*)(b3p0 + ko);
                short8v b31 = *(const short8v*)(b3p1 + ko);
                short8v b50 = *(const short8v*)(b5p0 + ko);
                short8v b51 = *(const short8v*)(b5p1 + ko);
                const int g0 = (ko >> 2) + kg * 2;   // even global chunk
#pragma unroll
                for (int m = 0; m < 4; ++m) {
                    const int row = m * 16 + l15;
                    const float* rp = es + (size_t)row * 128;
                    float4 f0 = *(const float4*)(rp + (((g0)     ^ sx) << 2));
                    float4 f1 = *(const float4*)(rp + (((g0 + 1) ^ sx) << 2));
                    short8v af;
                    af[0] = (short)f2bf(f0.x); af[1] = (short)f2bf(f0.y);
                    af[2] = (short)f2bf(f0.z); af[3] = (short)f2bf(f0.w);
                    af[4] = (short)f2bf(f1.x); af[5] = (short)f2bf(f1.y);
                    af[6] = (short)f2bf(f1.z); af[7] = (short)f2bf(f1.w);
                    a3[m][0] = __builtin_amdgcn_mfma_f32_16x16x32_bf16(af, b30, a3[m][0], 0, 0, 0);
                    a3[m][1] = __builtin_amdgcn_mfma_f32_16x16x32_bf16(af, b31, a3[m][1], 0, 0, 0);
                    a5[m][0] = __builtin_amdgcn_mfma_f32_16x16x32_bf16(af, b50, a5[m][0], 0, 0, 0);
                    a5[m][1] = __builtin_amdgcn_mfma_f32_16x16x32_bf16(af, b51, a5[m][1], 0, 0, 0);
                }
            }
        }

        // ---- epilogue: ex = exp(u*(v+x3)*inv) in place over a3; a5 *= ex ----
        // consumes the prefetched upk/vpk regs (oldest vmcnt slots: their wait
        // does NOT drain the younger stage DMAs)
#pragma unroll
        for (int m = 0; m < 4; ++m) {
#pragma unroll
            for (int r = 0; r < 4; ++r) {
                float u0 = bf2f((unsigned short)(upk[m][r] & 0xffffu));
                float u1 = bf2f((unsigned short)(upk[m][r] >> 16));
                float v0 = bf2f((unsigned short)(vpk[m][r] & 0xffffu));
                float v1 = bf2f((unsigned short)(vpk[m][r] >> 16));
                float at0 = u0 * (v0 + a3[m][0][r]) * inv;
                float at1 = u1 * (v1 + a3[m][1][r]) * inv;
                float ex0 = __expf(fminf(at0, 80.f));
                float ex1 = __expf(fminf(at1, 80.f));
                a3[m][0][r] = ex0;
                a3[m][1][r] = ex1;
                a5[m][0][r] = ex0 * a5[m][0][r];
                a5[m][1][r] = ex1 * a5[m][1][r];
            }
        }

        // ---- combined segmented reduce -> dpart, apart ----
        for (int sg = 0; sg < nseg; ++sg) {
            const int b  = __builtin_amdgcn_readfirstlane(s_sb[mi][sg]);
            const int e2 = __builtin_amdgcn_readfirstlane(s_se[mi][sg]);
            const int pi = __builtin_amdgcn_readfirstlane(s_pi[mi][sg]);
            float d0 = 0.f, d1 = 0.f, g0 = 0.f, g1 = 0.f;
#pragma unroll
            for (int m = 0; m < 4; ++m) {
                if (b < m * 16 + 16 && e2 > m * 16) {   // scalar branch: skip m-block
#pragma unroll
                    for (int r = 0; r < 4; ++r) {
                        int slot = m * 16 + kg * 4 + r;
                        bool in = (slot >= b) && (slot < e2);
                        d0 += in ? a3[m][0][r] : 0.f;
                        d1 += in ? a3[m][1][r] : 0.f;
                        g0 += in ? a5[m][0][r] : 0.f;
                        g1 += in ? a5[m][1][r] : 0.f;
                    }
                }
            }
            d0 += __shfl_xor(d0, 16); d0 += __shfl_xor(d0, 32);
            d1 += __shfl_xor(d1, 16); d1 += __shfl_xor(d1, 32);
            g0 += __shfl_xor(g0, 16); g0 += __shfl_xor(g0, 32);
            g1 += __shfl_xor(g1, 16); g1 += __shfl_xor(g1, 32);
            if (kg == 0) {
                *(float2*)&dpart[(size_t)pi * 128 + cb] = make_float2(d0, d1);
                *(float2*)&apart[(size_t)pi * 128 + cb] = make_float2(g0, g1);
            }
        }

        // ---- tail: wave0 ballots slot it+2 meta into meta[mi2] ----
        if (t < 64 && it < EDGE_SLOTS - 2) {
            int slot2 = b0 + (it + 2) * EDGE_GRID;
            s_eid[mi2][t] = m_eid; s_src[mi2][t] = m_src; s_dst[mi2][t] = m_dst;
            int dprev = __shfl_up(m_dst, 1);
            bool bnd = (t == 0) || (m_dst != dprev);
            unsigned long long mask = __ballot(bnd);
            int sid = __popcll(mask & ((1ull << t) - 1ull));
            if (bnd) {
                s_sb[mi2][sid] = t;
                s_pi[mi2][sid] = ppos[m_dst] + slot2 - (offsets[m_dst] >> 6);
                if (t > 0) s_se[mi2][sid - 1] = t;
            }
            if (t == 63) {
                int ns = __popcll(mask);
                s_se[mi2][ns - 1] = 64;
                s_nseg[mi2] = ns;
            }
        }
        // one barrier per slot: retires stage(it+1) (vmcnt drain) + meta(it+2)
        __syncthreads();
    }
}

// ---------- node finalize: sum pieces, h1 = LN(hw6 + k + agg/denom) ----------
__global__ __launch_bounds__(256) void node_finalize(
    const float* __restrict__ hw6f, const unsigned short* __restrict__ uvkb,
    const float* __restrict__ dpart, const float* __restrict__ apart,
    const int* __restrict__ ppos,
    const float* __restrict__ gamma, const float* __restrict__ beta,
    float* __restrict__ h1, unsigned short* __restrict__ h1b)
{
    int n = blockIdx.x * 4 + (threadIdx.x >> 6);
    int lane = threadIdx.x & 63;
    int p0 = ppos[n], p1 = ppos[n + 1];
    float de0 = 0.f, de1 = 0.f, g0 = 0.f, g1 = 0.f;
    for (int j = p0; j < p1; ++j) {
        float2 dv = *(const float2*)&dpart[(size_t)j * 128 + lane * 2];
        float2 av = *(const float2*)&apart[(size_t)j * 128 + lane * 2];
        de0 += dv.x; de1 += dv.y;
        g0  += av.x; g1  += av.y;
    }
    unsigned kpk = *(const unsigned*)&uvkb[(size_t)n * 384 + 256 + lane * 2];
    float k0 = bf2f((unsigned short)(kpk & 0xffffu));
    float k1 = bf2f((unsigned short)(kpk >> 16));
    float2 hw = *(const float2*)&hw6f[(size_t)n * 128 + lane * 2];
    float x0 = hw.x + (de0 > 0.f ? k0 + g0 / de0 : 0.f);
    float x1 = hw.y + (de1 > 0.f ? k1 + g1 / de1 : 0.f);
    float s = x0 + x1;
#pragma unroll
    for (int off = 1; off < 64; off <<= 1) s += __shfl_xor(s, off);
    float mu = s * (1.f / 128.f);
    float d0 = x0 - mu, d1 = x1 - mu;
    float ss = d0 * d0 + d1 * d1;
#pragma unroll
    for (int off = 1; off < 64; off <<= 1) ss += __shfl_xor(ss, off);
    float rs = rsqrtf(ss * (1.f / 128.f) + 1e-5f);
    float2 g = *(const float2*)&gamma[lane * 2];
    float2 b = *(const float2*)&beta[lane * 2];
    float o0 = d0 * rs * g.x + b.x;
    float o1 = d1 * rs * g.y + b.y;
    size_t base = (size_t)n * 128 + lane * 2;
    *(float2*)&h1[base] = make_float2(o0, o1);
    *(unsigned*)&h1b[base] = pack2(o0, o1);
}

extern "C" void kernel_launch(void* const* d_in, const int* in_sizes, int n_in,
                              void* d_out, int out_size, void* d_ws, size_t ws_size,
                              hipStream_t stream)
{
    const float* h    = (const float*)d_in[0];
    const float* e_ij = (const float*)d_in[1];
    const float* W1   = (const float*)d_in[2];
    const float* W2   = (const float*)d_in[3];
    const float* W3   = (const float*)d_in[4];
    const float* W4   = (const float*)d_in[5];
    const float* W5   = (const float*)d_in[6];
    const float* W6   = (const float*)d_in[7];
    const float* ln_g = (const float*)d_in[8];
    const float* ln_b = (const float*)d_in[9];
    const float* mw1  = (const float*)d_in[10];
    const float* mw2  = (const float*)d_in[11];
    const int*   src  = (const int*)d_in[12];
    const int*   dst  = (const int*)d_in[13];
    float* out = (float*)d_out;

    float* ws = (float*)d_ws;
    // layout (float offsets); P_max = 112640 pieces (N + E/64 rounded up)
    float* hw6f  = ws;                                 // [100k][128]
    float* h1    = ws + 12800000;                      // [100k][128]
    float* dpart = ws + 25600000;                      // [112640][128] = 14,417,920
    float* apart = ws + 40100000;                      // [112640][128]
    unsigned short* uvkb    = (unsigned short*)(ws + 54600000);   // [100k][384]
    unsigned short* h1b     = (unsigned short*)(ws + 73800000);   // [100k][128]
    unsigned short* hiddenb = (unsigned short*)(ws + 80200000);   // [100k][256]
    unsigned short* w3t   = (unsigned short*)(ws + 93000000);     // [128][128]
    unsigned short* w5t   = w3t + 16384;
    unsigned short* wcatt = w5t + 16384;               // [512][128]
    unsigned short* mw1t  = wcatt + 65536;             // [256][128]
    unsigned short* mw2t  = mw1t + 32768;              // [128][256]
    int* ibase    = (int*)(ws + 93100000);
    int* counts   = ibase;                             // [N]
    int* offsets  = ibase + 100000;                    // [N+1]
    int* cursor   = ibase + 200001;                    // [N]
    int* npieces  = ibase + 300001;                    // [N]
    int* ppos     = ibase + 400001;                    // [N+1]
    int* partials = ibase + 500102;                    // [128]
    int* edge_ord = ibase + 500230;                    // [E]
    int* src_ord  = edge_ord + N_EDGES;                // [E]
    int* dst_ord  = src_ord + N_EDGES;                 // [E]

    dim3 blk(256);
    hipMemsetAsync(counts, 0, N_NODES * sizeof(int), stream);

    hist_dst<<<N_EDGES / 256, blk, 0, stream>>>(dst, counts);
    scan_p1<<<98, blk, 0, stream>>>(counts, partials, N_NODES);
    scan_p2<<<1, 64, 0, stream>>>(partials, 98, offsets + N_NODES);
    scan_p3<<<98, blk, 0, stream>>>(counts, offsets, cursor, partials, N_NODES);
    scatter_edges<<<N_EDGES / 256, blk, 0, stream>>>(dst, src, cursor,
                                                     edge_ord, src_ord, dst_ord);
    calc_npieces<<<391, blk, 0, stream>>>(offsets, npieces);
    scan_p1<<<98, blk, 0, stream>>>(npieces, partials, N_NODES);
    scan_p2<<<1, 64, 0, stream>>>(partials, 98, ppos + N_NODES);
    scan_p3<<<98, blk, 0, stream>>>(npieces, ppos, (int*)nullptr, partials, N_NODES);

    prep_weights<<<576, blk, 0, stream>>>(W1, W2, W3, W4, W5, W6, mw1, mw2,
                                          w3t, w5t, wcatt, mw1t, mw2t);

    // u|v|k (bf16) and hw6 (f32) = h @ [W1|W2|W4|W6]  (A read f32, cvt in-reg)
    gemm_node<<<dim3(1563, 4), blk, 0, stream>>>(h, wcatt, uvkb, hw6f);

    edge_agg<<<EDGE_GRID, blk, 0, stream>>>(e_ij, w3t, w5t, uvkb,
                                            edge_ord, src_ord, dst_ord,
                                            offsets, ppos, dpart, apart);

    node_finalize<<<N_NODES / 4, blk, 0, stream>>>(hw6f, uvkb, dpart, apart, ppos,
                                                   ln_g, ln_b, h1, h1b);

    // hidden = relu(h1 @ mw1)
    gemm_bf16<<<dim3(1563, 2), blk, 0, stream>>>(h1b, mw1t, N_NODES, 128, 256,
                                                 nullptr, nullptr, hiddenb, 1);
    // out = LN(hidden @ mw2 + h1)
    gemm_bf16_ln<<<1563, blk, 0, stream>>>(hiddenb, mw2t, N_NODES, 256,
                                           h1, ln_g, ln_b, out);
}

// Round 5
// 629.086 us; speedup vs baseline: 1.7835x; 1.3301x over previous
//
#include <hip/hip_runtime.h>
#include <hip/hip_bf16.h>

#define N_NODES 100000
#define N_EDGES 800000

typedef __attribute__((ext_vector_type(8))) short short8v;   // 8 bf16 = 4 VGPRs
typedef __attribute__((ext_vector_type(4))) float f32x4;

__device__ __forceinline__ unsigned short f2bf(float f) {
    __hip_bfloat16 b = __float2bfloat16(f);
    return *(unsigned short*)&b;
}
__device__ __forceinline__ float bf2f(unsigned short u) {
    return __uint_as_float((unsigned)u << 16);
}
__device__ __forceinline__ unsigned pack2(float lo, float hi) {
    return (unsigned)f2bf(lo) | ((unsigned)f2bf(hi) << 16);
}

// async 16B global->LDS DMA (gfx950). LDS dest: wave-uniform base + lane*16.
__device__ __forceinline__ void gload_lds16(const void* g, void* l) {
    __builtin_amdgcn_global_load_lds(
        (const __attribute__((address_space(1))) unsigned int*)g,
        (__attribute__((address_space(3))) unsigned int*)l,
        16, 0, 0);
}

// ---------- CSR build ----------
__global__ __launch_bounds__(256) void hist_dst(
    const int* __restrict__ dst, int* __restrict__ counts)
{
    int e = blockIdx.x * 256 + threadIdx.x;
    if (e < N_EDGES) atomicAdd(&counts[dst[e]], 1);
}

__global__ __launch_bounds__(256) void scan_p1(
    const int* __restrict__ in, int* __restrict__ partials, int n)
{
    __shared__ int ws[4];
    int t = threadIdx.x, lane = t & 63, wv = t >> 6;
    int base = blockIdx.x * 1024;
    int s = 0;
#pragma unroll
    for (int i = 0; i < 4; ++i) {
        int idx = base + i * 256 + t;
        s += (idx < n) ? in[idx] : 0;
    }
#pragma unroll
    for (int off = 1; off < 64; off <<= 1) s += __shfl_xor(s, off);
    if (lane == 0) ws[wv] = s;
    __syncthreads();
    if (t == 0) partials[blockIdx.x] = ws[0] + ws[1] + ws[2] + ws[3];
}

__global__ __launch_bounds__(64) void scan_p2(
    int* __restrict__ partials, int nb, int* __restrict__ total_out)
{
    int lane = threadIdx.x;
    int carry = 0;
    for (int base = 0; base < nb; base += 64) {
        int idx = base + lane;
        int v = (idx < nb) ? partials[idx] : 0;
        int s = v;
#pragma unroll
        for (int off = 1; off < 64; off <<= 1) {
            int w = __shfl_up(s, off);
            if (lane >= off) s += w;
        }
        if (idx < nb) partials[idx] = s - v + carry;
        carry += __shfl(s, 63);
    }
    if (lane == 0) *total_out = carry;
}

__global__ __launch_bounds__(256) void scan_p3(
    const int* __restrict__ in, int* __restrict__ out, int* __restrict__ cursor,
    const int* __restrict__ partials, int n)
{
    __shared__ int ws[4];
    __shared__ int wpre[4];
    __shared__ int s_tot;
    int t = threadIdx.x, lane = t & 63, wv = t >> 6;
    int base = blockIdx.x * 1024;
    int carry = partials[blockIdx.x];
    for (int sub = 0; sub < 4; ++sub) {
        int idx = base + sub * 256 + t;
        int v = (idx < n) ? in[idx] : 0;
        int s = v;
#pragma unroll
        for (int off = 1; off < 64; off <<= 1) {
            int w = __shfl_up(s, off);
            if (lane >= off) s += w;
        }
        if (lane == 63) ws[wv] = s;
        __syncthreads();
        if (t == 0) {
            int a = 0;
#pragma unroll
            for (int i = 0; i < 4; ++i) { wpre[i] = a; a += ws[i]; }
            s_tot = a;
        }
        __syncthreads();
        int excl = s - v + wpre[wv] + carry;
        if (idx < n) { out[idx] = excl; if (cursor) cursor[idx] = excl; }
        carry += s_tot;
        __syncthreads();
    }
}

__global__ __launch_bounds__(256) void scatter_edges(
    const int* __restrict__ dst, const int* __restrict__ src,
    int* __restrict__ cursor,
    int* __restrict__ edge_ord, int* __restrict__ src_ord,
    int* __restrict__ dst_ord)
{
    int e = blockIdx.x * 256 + threadIdx.x;
    if (e < N_EDGES) {
        int d = dst[e];
        int pos = atomicAdd(&cursor[d], 1);
        edge_ord[pos] = e;
        src_ord[pos] = src[e];
        dst_ord[pos] = d;
    }
}

// npieces[n] = number of 64-slot blocks node n's slot range touches
__global__ __launch_bounds__(256) void calc_npieces(
    const int* __restrict__ offsets, int* __restrict__ npieces)
{
    int n = blockIdx.x * 256 + threadIdx.x;
    if (n < N_NODES) {
        int b = offsets[n], e = offsets[n + 1];
        npieces[n] = (e > b) ? (((e - 1) >> 6) - (b >> 6) + 1) : 0;
    }
}

// ---------- fused weight prep: w3t,w5t | wcatt | mw1t,mw2t ----------
__global__ __launch_bounds__(256) void prep_weights(
    const float* __restrict__ W1, const float* __restrict__ W2,
    const float* __restrict__ W3, const float* __restrict__ W4,
    const float* __restrict__ W5, const float* __restrict__ W6,
    const float* __restrict__ mw1, const float* __restrict__ mw2,
    unsigned short* __restrict__ w3t, unsigned short* __restrict__ w5t,
    unsigned short* __restrict__ wcatt,
    unsigned short* __restrict__ mw1t, unsigned short* __restrict__ mw2t)
{
    int bid = blockIdx.x;
    if (bid < 64) {
        int t = bid * 256 + threadIdx.x;          // 0..16383
        int r = t >> 7, c = t & 127;
        w3t[c * 128 + r] = f2bf(W3[t]);
        w5t[c * 128 + r] = f2bf(W5[t]);
    } else if (bid < 320) {
        int t = (bid - 64) * 256 + threadIdx.x;   // 0..65535
        int n = t >> 7, k = t & 127;
        const float* Wm = (n < 128) ? W1 : (n < 256) ? W2 : (n < 384) ? W4 : W6;
        wcatt[t] = f2bf(Wm[k * 128 + (n & 127)]);
    } else {
        int t = (bid - 320) * 256 + threadIdx.x;  // 0..65535
        if (t < 32768) {
            int n = t >> 7, k = t & 127;
            mw1t[t] = f2bf(mw1[k * 256 + n]);
        } else {
            int s = t - 32768;
            int n = s >> 8, k = s & 255;
            mw2t[s] = f2bf(mw2[k * 128 + n]);
        }
    }
}

// ---------- node GEMM: [u|v|k] bf16 + hw6 f32 = h(f32) @ [W1|W2|W4|W6] ----------
__global__ __launch_bounds__(256) void gemm_node(
    const float* __restrict__ A, const unsigned short* __restrict__ Bt,
    unsigned short* __restrict__ uvkb, float* __restrict__ hw6f)
{
    const int t = threadIdx.x;
    const int lane = t & 63, wv = t >> 6;
    const int l15 = lane & 15, kg = lane >> 4;
    const int m0 = blockIdx.x * 64;
    const int n0 = blockIdx.y * 128;
    const int M = N_NODES, K = 128;

    int arow = m0 + wv * 16 + l15;
    int arow_c = arow < M ? arow : M - 1;
    const float* ap = A + (size_t)arow_c * K + kg * 8;

    f32x4 acc[8];
#pragma unroll
    for (int nt = 0; nt < 8; ++nt) acc[nt] = (f32x4){0.f, 0.f, 0.f, 0.f};

    for (int ko = 0; ko < K; ko += 32) {
        float4 f0 = *(const float4*)(ap + ko);
        float4 f1 = *(const float4*)(ap + ko + 4);
        short8v af;
        af[0] = (short)f2bf(f0.x); af[1] = (short)f2bf(f0.y);
        af[2] = (short)f2bf(f0.z); af[3] = (short)f2bf(f0.w);
        af[4] = (short)f2bf(f1.x); af[5] = (short)f2bf(f1.y);
        af[6] = (short)f2bf(f1.z); af[7] = (short)f2bf(f1.w);
#pragma unroll
        for (int nt = 0; nt < 8; ++nt) {
            short8v bf = *(const short8v*)(Bt + (size_t)(n0 + nt * 16 + l15) * K + ko + kg * 8);
            acc[nt] = __builtin_amdgcn_mfma_f32_16x16x32_bf16(af, bf, acc[nt], 0, 0, 0);
        }
    }
#pragma unroll
    for (int nt = 0; nt < 8; ++nt) {
#pragma unroll
        for (int r = 0; r < 4; ++r) {
            int row = m0 + wv * 16 + kg * 4 + r;
            if (row < M) {
                int col = n0 + nt * 16 + l15;
                float vfl = acc[nt][r];
                if (n0 < 384) uvkb[(size_t)row * 384 + col] = f2bf(vfl);
                else          hw6f[(size_t)row * 128 + col - 384] = vfl;
            }
        }
    }
}

// ---------- generic bf16 MFMA GEMM (MLP hidden) ----------
__global__ __launch_bounds__(256) void gemm_bf16(
    const unsigned short* __restrict__ A, const unsigned short* __restrict__ Bt,
    int M, int K, int Nc,
    const float* __restrict__ res, float* __restrict__ Cf,
    unsigned short* __restrict__ Cb, int do_relu)
{
    const int t = threadIdx.x;
    const int lane = t & 63, wv = t >> 6;
    const int l15 = lane & 15, kg = lane >> 4;
    const int m0 = blockIdx.x * 64;
    const int n0 = blockIdx.y * 128;

    int arow = m0 + wv * 16 + l15;
    int arow_c = arow < M ? arow : M - 1;
    const unsigned short* ap = A + (size_t)arow_c * K + kg * 8;

    f32x4 acc[8];
#pragma unroll
    for (int nt = 0; nt < 8; ++nt) acc[nt] = (f32x4){0.f, 0.f, 0.f, 0.f};

    for (int ko = 0; ko < K; ko += 32) {
        short8v af = *(const short8v*)(ap + ko);
#pragma unroll
        for (int nt = 0; nt < 8; ++nt) {
            short8v bf = *(const short8v*)(Bt + (size_t)(n0 + nt * 16 + l15) * K + ko + kg * 8);
            acc[nt] = __builtin_amdgcn_mfma_f32_16x16x32_bf16(af, bf, acc[nt], 0, 0, 0);
        }
    }
#pragma unroll
    for (int nt = 0; nt < 8; ++nt) {
#pragma unroll
        for (int r = 0; r < 4; ++r) {
            int row = m0 + wv * 16 + kg * 4 + r;
            if (row < M) {
                int col = n0 + nt * 16 + l15;
                float vfl = acc[nt][r];
                if (res) vfl += res[(size_t)row * Nc + col];
                if (do_relu) vfl = fmaxf(vfl, 0.f);
                if (Cf) Cf[(size_t)row * Nc + col] = vfl;
                else    Cb[(size_t)row * Nc + col] = f2bf(vfl);
            }
        }
    }
}

// ---------- mw2 GEMM + residual + LayerNorm fused (Nc = 128) ----------
__global__ __launch_bounds__(256) void gemm_bf16_ln(
    const unsigned short* __restrict__ A, const unsigned short* __restrict__ Bt,
    int M, int K, const float* __restrict__ res,
    const float* __restrict__ gamma, const float* __restrict__ beta,
    float* __restrict__ out)
{
    const int t = threadIdx.x;
    const int lane = t & 63, wv = t >> 6;
    const int l15 = lane & 15, kg = lane >> 4;
    const int m0 = blockIdx.x * 64;

    int arow = m0 + wv * 16 + l15;
    int arow_c = arow < M ? arow : M - 1;
    const unsigned short* ap = A + (size_t)arow_c * K + kg * 8;

    f32x4 acc[8];
#pragma unroll
    for (int nt = 0; nt < 8; ++nt) acc[nt] = (f32x4){0.f, 0.f, 0.f, 0.f};

    for (int ko = 0; ko < K; ko += 32) {
        short8v af = *(const short8v*)(ap + ko);
#pragma unroll
        for (int nt = 0; nt < 8; ++nt) {
            short8v bf = *(const short8v*)(Bt + (size_t)(nt * 16 + l15) * K + ko + kg * 8);
            acc[nt] = __builtin_amdgcn_mfma_f32_16x16x32_bf16(af, bf, acc[nt], 0, 0, 0);
        }
    }

    float gv[8], bv[8];
#pragma unroll
    for (int nt = 0; nt < 8; ++nt) {
        gv[nt] = gamma[nt * 16 + l15];
        bv[nt] = beta[nt * 16 + l15];
    }

#pragma unroll
    for (int r = 0; r < 4; ++r) {
        int row = m0 + wv * 16 + kg * 4 + r;
        int rc = row < M ? row : M - 1;
        float x[8];
        float s = 0.f;
#pragma unroll
        for (int nt = 0; nt < 8; ++nt) {
            x[nt] = acc[nt][r] + res[(size_t)rc * 128 + nt * 16 + l15];
            s += x[nt];
        }
#pragma unroll
        for (int off = 1; off < 16; off <<= 1) s += __shfl_xor(s, off);
        float mu = s * (1.f / 128.f);
        float ss = 0.f;
#pragma unroll
        for (int nt = 0; nt < 8; ++nt) {
            float d = x[nt] - mu;
            ss += d * d;
        }
#pragma unroll
        for (int off = 1; off < 16; off <<= 1) ss += __shfl_xor(ss, off);
        float rsv = rsqrtf(ss * (1.f / 128.f) + 1e-5f);
        if (row < M) {
#pragma unroll
            for (int nt = 0; nt < 8; ++nt)
                out[(size_t)row * 128 + nt * 16 + l15] =
                    (x[nt] - mu) * rsv * gv[nt] + bv[nt];
        }
    }
}

// ---------- fused edge pass + in-register segmented aggregation ----------
// v18: ONE-SHOT blocks (v13 grid, 12500 x 64 edges) with the best pieces of
// v16/v17: async global_load_lds stage of the f32 e-tile (no stage VALU, 32KB
// burst in flight per block) + fused W3/W5 K-pass (e read from LDS once) +
// XOR-preswizzled source / XOR read. LDS = 32KB tile + 1.6KB meta -> 4
// blocks/CU resident; block-level TLP hides the DMA drain and gather latency
// (the mechanism v16/v17's 69KB double-buffer destroyed -- occupancy 11.6%).
// __launch_bounds__(256,4) caps VGPR at 128 for the 4-block residency; uvkb
// u/v gathers are direct loads in the epilogue (short liveness, no spill).
__global__ __launch_bounds__(256, 4) void edge_agg(
    const float* __restrict__ e_ij,
    const unsigned short* __restrict__ w3t, const unsigned short* __restrict__ w5t,
    const unsigned short* __restrict__ uvkb,
    const int* __restrict__ edge_ord, const int* __restrict__ src_ord,
    const int* __restrict__ dst_ord,
    const int* __restrict__ offsets, const int* __restrict__ ppos,
    float* __restrict__ dpart, float* __restrict__ apart)
{
    __shared__ __align__(16) float e_s[64 * 128];   // 32 KB f32
    __shared__ int s_eid[64], s_src[64], s_dst[64];
    __shared__ int s_sb[64], s_se[64], s_pi[64];
    __shared__ int s_nseg;

    const int t  = threadIdx.x;
    const int lane = t & 63, wv = t >> 6;
    const int l15 = lane & 15, kg = lane >> 4;
    const int cb = wv * 32 + 2 * l15;              // this lane's col pair
    const float inv = 0.17677669529663687f;        // 1/sqrt(32)
    const int e0 = blockIdx.x * 64;
    const int sx = l15 & 7;                        // read-side XOR key (= row&7)

    // ---- meta: wave 0 ballots segments ----
    if (t < 64) {
        s_eid[t] = edge_ord[e0 + t];
        s_src[t] = src_ord[e0 + t];
        int d = dst_ord[e0 + t];
        s_dst[t] = d;
        int dprev = __shfl_up(d, 1);
        bool bnd = (t == 0) || (d != dprev);
        unsigned long long mask = __ballot(bnd);
        int sid = __popcll(mask & ((1ull << t) - 1ull));
        if (bnd) {
            s_sb[sid] = t;
            s_pi[sid] = ppos[d] + (int)blockIdx.x - (offsets[d] >> 6);
            if (t > 0) s_se[sid - 1] = t;
        }
        if (t == 63) {
            int ns = __popcll(mask);
            s_se[ns - 1] = 64;
            s_nseg = ns;
        }
    }
    __syncthreads();

    // ---- async DMA stage: 2048 chunks of 16B; thread t covers chunk i*256+t.
    // LDS chunk (row, j) receives global chunk j^(row&7) of row eid[row].
#pragma unroll
    for (int i = 0; i < 8; ++i) {
        int c = i * 256 + t;
        int row = c >> 5, j = c & 31;
        int js = j ^ (row & 7);
        const float* g = e_ij + (size_t)s_eid[row] * 128 + js * 4;
        void* l = (void*)((char*)(&e_s[0]) + (size_t)i * 4096 + (size_t)wv * 1024);
        gload_lds16(g, l);
    }
    __syncthreads();   // drain: tile staged (other resident blocks compute meanwhile)

    const int nseg = __builtin_amdgcn_readfirstlane(s_nseg);
    const float* es = &e_s[0];

    // ---- fused K-pass: a3 = e@W3 cols, a5 = e@W5 cols (same A frags) ----
    f32x4 a3[4][2], a5[4][2];
#pragma unroll
    for (int m = 0; m < 4; ++m) {
        a3[m][0] = (f32x4){0.f, 0.f, 0.f, 0.f};
        a3[m][1] = (f32x4){0.f, 0.f, 0.f, 0.f};
        a5[m][0] = (f32x4){0.f, 0.f, 0.f, 0.f};
        a5[m][1] = (f32x4){0.f, 0.f, 0.f, 0.f};
    }
    {
        const unsigned short* b3p0 = w3t + (size_t)(cb + 0) * 128 + kg * 8;
        const unsigned short* b3p1 = w3t + (size_t)(cb + 1) * 128 + kg * 8;
        const unsigned short* b5p0 = w5t + (size_t)(cb + 0) * 128 + kg * 8;
        const unsigned short* b5p1 = w5t + (size_t)(cb + 1) * 128 + kg * 8;
#pragma unroll
        for (int kidx = 0; kidx < 4; ++kidx) {
            const int ko = kidx * 32;
            short8v b30 = *(const short8v*)(b3p0 + ko);
            short8v b31 = *(const short8v*)(b3p1 + ko);
            short8v b50 = *(const short8v*)(b5p0 + ko);
            short8v b51 = *(const short8v*)(b5p1 + ko);
            const int g0 = (ko >> 2) + kg * 2;   // even global chunk
#pragma unroll
            for (int m = 0; m < 4; ++m) {
                const int row = m * 16 + l15;
                const float* rp = es + (size_t)row * 128;
                float4 f0 = *(const float4*)(rp + (((g0)     ^ sx) << 2));
                float4 f1 = *(const float4*)(rp + (((g0 + 1) ^ sx) << 2));
                short8v af;
                af[0] = (short)f2bf(f0.x); af[1] = (short)f2bf(f0.y);
                af[2] = (short)f2bf(f0.z); af[3] = (short)f2bf(f0.w);
                af[4] = (short)f2bf(f1.x); af[5] = (short)f2bf(f1.y);
                af[6] = (short)f2bf(f1.z); af[7] = (short)f2bf(f1.w);
                a3[m][0] = __builtin_amdgcn_mfma_f32_16x16x32_bf16(af, b30, a3[m][0], 0, 0, 0);
                a3[m][1] = __builtin_amdgcn_mfma_f32_16x16x32_bf16(af, b31, a3[m][1], 0, 0, 0);
                a5[m][0] = __builtin_amdgcn_mfma_f32_16x16x32_bf16(af, b50, a5[m][0], 0, 0, 0);
                a5[m][1] = __builtin_amdgcn_mfma_f32_16x16x32_bf16(af, b51, a5[m][1], 0, 0, 0);
            }
        }
    }

    // ---- epilogue: ex = exp(u*(v+x3)*inv) in place over a3; a5 *= ex ----
    // direct uvkb gathers (short liveness; batched by the unroller, latency
    // overlapped by the 3 other resident blocks)
#pragma unroll
    for (int m = 0; m < 4; ++m) {
#pragma unroll
        for (int r = 0; r < 4; ++r) {
            int le = m * 16 + kg * 4 + r;
            int d  = s_dst[le];
            int sv = s_src[le];
            unsigned upk = *(const unsigned*)&uvkb[(size_t)sv * 384 + cb];
            unsigned vpk = *(const unsigned*)&uvkb[(size_t)d * 384 + 128 + cb];
            float u0 = bf2f((unsigned short)(upk & 0xffffu));
            float u1 = bf2f((unsigned short)(upk >> 16));
            float v0 = bf2f((unsigned short)(vpk & 0xffffu));
            float v1 = bf2f((unsigned short)(vpk >> 16));
            float at0 = u0 * (v0 + a3[m][0][r]) * inv;
            float at1 = u1 * (v1 + a3[m][1][r]) * inv;
            float ex0 = __expf(fminf(at0, 80.f));
            float ex1 = __expf(fminf(at1, 80.f));
            a3[m][0][r] = ex0;
            a3[m][1][r] = ex1;
            a5[m][0][r] = ex0 * a5[m][0][r];
            a5[m][1][r] = ex1 * a5[m][1][r];
        }
    }

    // ---- combined segmented reduce -> dpart, apart ----
    for (int sg = 0; sg < nseg; ++sg) {
        const int b  = __builtin_amdgcn_readfirstlane(s_sb[sg]);
        const int e2 = __builtin_amdgcn_readfirstlane(s_se[sg]);
        const int pi = __builtin_amdgcn_readfirstlane(s_pi[sg]);
        float d0 = 0.f, d1 = 0.f, g0 = 0.f, g1 = 0.f;
#pragma unroll
        for (int m = 0; m < 4; ++m) {
            if (b < m * 16 + 16 && e2 > m * 16) {   // scalar branch: skip m-block
#pragma unroll
                for (int r = 0; r < 4; ++r) {
                    int slot = m * 16 + kg * 4 + r;
                    bool in = (slot >= b) && (slot < e2);
                    d0 += in ? a3[m][0][r] : 0.f;
                    d1 += in ? a3[m][1][r] : 0.f;
                    g0 += in ? a5[m][0][r] : 0.f;
                    g1 += in ? a5[m][1][r] : 0.f;
                }
            }
        }
        d0 += __shfl_xor(d0, 16); d0 += __shfl_xor(d0, 32);
        d1 += __shfl_xor(d1, 16); d1 += __shfl_xor(d1, 32);
        g0 += __shfl_xor(g0, 16); g0 += __shfl_xor(g0, 32);
        g1 += __shfl_xor(g1, 16); g1 += __shfl_xor(g1, 32);
        if (kg == 0) {
            *(float2*)&dpart[(size_t)pi * 128 + cb] = make_float2(d0, d1);
            *(float2*)&apart[(size_t)pi * 128 + cb] = make_float2(g0, g1);
        }
    }
}

// ---------- node finalize: sum pieces, h1 = LN(hw6 + k + agg/denom) ----------
__global__ __launch_bounds__(256) void node_finalize(
    const float* __restrict__ hw6f, const unsigned short* __restrict__ uvkb,
    const float* __restrict__ dpart, const float* __restrict__ apart,
    const int* __restrict__ ppos,
    const float* __restrict__ gamma, const float* __restrict__ beta,
    float* __restrict__ h1, unsigned short* __restrict__ h1b)
{
    int n = blockIdx.x * 4 + (threadIdx.x >> 6);
    int lane = threadIdx.x & 63;
    int p0 = ppos[n], p1 = ppos[n + 1];
    float de0 = 0.f, de1 = 0.f, g0 = 0.f, g1 = 0.f;
    for (int j = p0; j < p1; ++j) {
        float2 dv = *(const float2*)&dpart[(size_t)j * 128 + lane * 2];
        float2 av = *(const float2*)&apart[(size_t)j * 128 + lane * 2];
        de0 += dv.x; de1 += dv.y;
        g0  += av.x; g1  += av.y;
    }
    unsigned kpk = *(const unsigned*)&uvkb[(size_t)n * 384 + 256 + lane * 2];
    float k0 = bf2f((unsigned short)(kpk & 0xffffu));
    float k1 = bf2f((unsigned short)(kpk >> 16));
    float2 hw = *(const float2*)&hw6f[(size_t)n * 128 + lane * 2];
    float x0 = hw.x + (de0 > 0.f ? k0 + g0 / de0 : 0.f);
    float x1 = hw.y + (de1 > 0.f ? k1 + g1 / de1 : 0.f);
    float s = x0 + x1;
#pragma unroll
    for (int off = 1; off < 64; off <<= 1) s += __shfl_xor(s, off);
    float mu = s * (1.f / 128.f);
    float d0 = x0 - mu, d1 = x1 - mu;
    float ss = d0 * d0 + d1 * d1;
#pragma unroll
    for (int off = 1; off < 64; off <<= 1) ss += __shfl_xor(ss, off);
    float rs = rsqrtf(ss * (1.f / 128.f) + 1e-5f);
    float2 g = *(const float2*)&gamma[lane * 2];
    float2 b = *(const float2*)&beta[lane * 2];
    float o0 = d0 * rs * g.x + b.x;
    float o1 = d1 * rs * g.y + b.y;
    size_t base = (size_t)n * 128 + lane * 2;
    *(float2*)&h1[base] = make_float2(o0, o1);
    *(unsigned*)&h1b[base] = pack2(o0, o1);
}

extern "C" void kernel_launch(void* const* d_in, const int* in_sizes, int n_in,
                              void* d_out, int out_size, void* d_ws, size_t ws_size,
                              hipStream_t stream)
{
    const float* h    = (const float*)d_in[0];
    const float* e_ij = (const float*)d_in[1];
    const float* W1   = (const float*)d_in[2];
    const float* W2   = (const float*)d_in[3];
    const float* W3   = (const float*)d_in[4];
    const float* W4   = (const float*)d_in[5];
    const float* W5   = (const float*)d_in[6];
    const float* W6   = (const float*)d_in[7];
    const float* ln_g = (const float*)d_in[8];
    const float* ln_b = (const float*)d_in[9];
    const float* mw1  = (const float*)d_in[10];
    const float* mw2  = (const float*)d_in[11];
    const int*   src  = (const int*)d_in[12];
    const int*   dst  = (const int*)d_in[13];
    float* out = (float*)d_out;

    float* ws = (float*)d_ws;
    // layout (float offsets); P_max = 112640 pieces (N + E/64 rounded up)
    float* hw6f  = ws;                                 // [100k][128]
    float* h1    = ws + 12800000;                      // [100k][128]
    float* dpart = ws + 25600000;                      // [112640][128] = 14,417,920
    float* apart = ws + 40100000;                      // [112640][128]
    unsigned short* uvkb    = (unsigned short*)(ws + 54600000);   // [100k][384]
    unsigned short* h1b     = (unsigned short*)(ws + 73800000);   // [100k][128]
    unsigned short* hiddenb = (unsigned short*)(ws + 80200000);   // [100k][256]
    unsigned short* w3t   = (unsigned short*)(ws + 93000000);     // [128][128]
    unsigned short* w5t   = w3t + 16384;
    unsigned short* wcatt = w5t + 16384;               // [512][128]
    unsigned short* mw1t  = wcatt + 65536;             // [256][128]
    unsigned short* mw2t  = mw1t + 32768;              // [128][256]
    int* ibase    = (int*)(ws + 93100000);
    int* counts   = ibase;                             // [N]
    int* offsets  = ibase + 100000;                    // [N+1]
    int* cursor   = ibase + 200001;                    // [N]
    int* npieces  = ibase + 300001;                    // [N]
    int* ppos     = ibase + 400001;                    // [N+1]
    int* partials = ibase + 500102;                    // [128]
    int* edge_ord = ibase + 500230;                    // [E]
    int* src_ord  = edge_ord + N_EDGES;                // [E]
    int* dst_ord  = src_ord + N_EDGES;                 // [E]

    dim3 blk(256);
    hipMemsetAsync(counts, 0, N_NODES * sizeof(int), stream);

    hist_dst<<<N_EDGES / 256, blk, 0, stream>>>(dst, counts);
    scan_p1<<<98, blk, 0, stream>>>(counts, partials, N_NODES);
    scan_p2<<<1, 64, 0, stream>>>(partials, 98, offsets + N_NODES);
    scan_p3<<<98, blk, 0, stream>>>(counts, offsets, cursor, partials, N_NODES);
    scatter_edges<<<N_EDGES / 256, blk, 0, stream>>>(dst, src, cursor,
                                                     edge_ord, src_ord, dst_ord);
    calc_npieces<<<391, blk, 0, stream>>>(offsets, npieces);
    scan_p1<<<98, blk, 0, stream>>>(npieces, partials, N_NODES);
    scan_p2<<<1, 64, 0, stream>>>(partials, 98, ppos + N_NODES);
    scan_p3<<<98, blk, 0, stream>>>(npieces, ppos, (int*)nullptr, partials, N_NODES);

    prep_weights<<<576, blk, 0, stream>>>(W1, W2, W3, W4, W5, W6, mw1, mw2,
                                          w3t, w5t, wcatt, mw1t, mw2t);

    // u|v|k (bf16) and hw6 (f32) = h @ [W1|W2|W4|W6]  (A read f32, cvt in-reg)
    gemm_node<<<dim3(1563, 4), blk, 0, stream>>>(h, wcatt, uvkb, hw6f);

    edge_agg<<<N_EDGES / 64, blk, 0, stream>>>(e_ij, w3t, w5t, uvkb,
                                               edge_ord, src_ord, dst_ord,
                                               offsets, ppos, dpart, apart);

    node_finalize<<<N_NODES / 4, blk, 0, stream>>>(hw6f, uvkb, dpart, apart, ppos,
                                                   ln_g, ln_b, h1, h1b);

    // hidden = relu(h1 @ mw1)
    gemm_bf16<<<dim3(1563, 2), blk, 0, stream>>>(h1b, mw1t, N_NODES, 128, 256,
                                                 nullptr, nullptr, hiddenb, 1);
    // out = LN(hidden @ mw2 + h1)
    gemm_bf16_ln<<<1563, blk, 0, stream>>>(hiddenb, mw2t, N_NODES, 256,
                                           h1, ln_g, ln_b, out);
}